// Round 1
// baseline (1031.524 us; speedup 1.0000x reference)
//
#include <hip/hip_runtime.h>
#include <hip/hip_bf16.h>

#define BN_EPS 1e-5f

// ---------------------------------------------------------------- graph prep

static __global__ void init_deg_cnt(float* deg, int* cnt, int N) {
  int i = blockIdx.x * blockDim.x + threadIdx.x;
  if (i < N) { deg[i] = 1.0f; cnt[i] = 0; }  // self-loop weight 1.0
}

static __global__ void hist_kernel(const int* __restrict__ col,
                                   const float* __restrict__ ew,
                                   float* deg, int* cnt, int E) {
  int e = blockIdx.x * blockDim.x + threadIdx.x;
  if (e < E) {
    int c = col[e];
    atomicAdd(&deg[c], ew[e]);
    atomicAdd(&cnt[c], 1);
  }
}

static __global__ void dis_kernel(float* deg, int N) {
  int i = blockIdx.x * blockDim.x + threadIdx.x;
  if (i < N) {
    float d = deg[i];
    deg[i] = d > 0.f ? rsqrtf(fmaxf(d, 1e-30f)) : 0.f;  // in-place: deg -> dis
  }
}

#define SCAN_B 256
#define SCAN_I 4
static __global__ void scanA(const int* __restrict__ cnt, int* __restrict__ start,
                             int* __restrict__ blkSum, int N) {
  __shared__ int sh[SCAN_B];
  int t = threadIdx.x;
  int base = blockIdx.x * SCAN_B * SCAN_I + t * SCAN_I;
  int v[SCAN_I];
  int tot = 0;
#pragma unroll
  for (int j = 0; j < SCAN_I; ++j) {
    v[j] = (base + j < N) ? cnt[base + j] : 0;
    tot += v[j];
  }
  sh[t] = tot;
  __syncthreads();
  int self = tot;
  for (int off = 1; off < SCAN_B; off <<= 1) {
    int add = (t >= off) ? sh[t - off] : 0;
    __syncthreads();
    sh[t] += add;
    __syncthreads();
  }
  int excl = sh[t] - self;
  if (t == SCAN_B - 1) blkSum[blockIdx.x] = sh[t];
  int run = excl;
#pragma unroll
  for (int j = 0; j < SCAN_I; ++j) {
    if (base + j < N) start[base + j] = run;
    run += v[j];
  }
}

static __global__ void scanB(const int* __restrict__ blkSum, int* __restrict__ blkOff, int nb) {
  __shared__ int sh[256];
  int t = threadIdx.x;
  int v = (t < nb) ? blkSum[t] : 0;
  sh[t] = v;
  __syncthreads();
  for (int off = 1; off < 256; off <<= 1) {
    int add = (t >= off) ? sh[t - off] : 0;
    __syncthreads();
    sh[t] += add;
    __syncthreads();
  }
  if (t < nb) blkOff[t] = sh[t] - v;
}

static __global__ void scanC(int* start, int* cursor, const int* __restrict__ blkOff, int N) {
  int i = blockIdx.x * blockDim.x + threadIdx.x;
  if (i < N) {
    int s = start[i] + blkOff[i / (SCAN_B * SCAN_I)];
    start[i] = s;
    cursor[i] = s;
  }
}

static __global__ void scatter_kernel(const int* __restrict__ row, const int* __restrict__ col,
                                      const float* __restrict__ ew, const float* __restrict__ dis,
                                      int* cursor, int* __restrict__ src_s,
                                      float* __restrict__ norm_s, int E) {
  int e = blockIdx.x * blockDim.x + threadIdx.x;
  if (e < E) {
    int r = row[e], c = col[e];
    int pos = atomicAdd(&cursor[c], 1);
    src_s[pos] = r;
    norm_s[pos] = dis[r] * ew[e] * dis[c];
  }
}

// ---------------------------------------------------------------- pack [W1|Wres]

static __global__ void pack_w(const float* __restrict__ W1, const float* __restrict__ Wres,
                              float* __restrict__ Wcat, int K, int H) {
  int i = blockIdx.x * blockDim.x + threadIdx.x;
  int total = K * 2 * H;
  if (i < total) {
    int k = i / (2 * H), j = i % (2 * H);
    Wcat[i] = (j < H) ? W1[k * H + j] : Wres[k * H + (j - H)];
  }
}

// ---------------------------------------------------------------- fp32 GEMM
// C = A[MxK] * B[KxN]; cols < split -> C0 (ld=split), cols >= split -> C1 (ld=N-split).
// Tile 64x128, 256 threads, 4x8 per thread. Output buffers padded to Mp rows.

#define GT_M 64
#define GT_N 128
#define GT_K 16

static __global__ __launch_bounds__(256)
void gemm_kernel(const float* __restrict__ A, const float* __restrict__ B,
                 float* __restrict__ C0, float* __restrict__ C1,
                 int M, int N, int K, int split) {
  __shared__ float As[GT_K][GT_M + 4];
  __shared__ float Bs[GT_K][GT_N];
  int t = threadIdx.x;
  int m0 = blockIdx.x * GT_M;
  int n0 = blockIdx.y * GT_N;
  int tx = t & 15, ty = t >> 4;
  int ar = t >> 2;          // 0..63 row in tile
  int ak = (t & 3) << 2;    // 0,4,8,12
  int bk = t >> 5;          // 0..7
  int bc = (t & 31) << 2;   // 0..124

  float acc[4][8];
#pragma unroll
  for (int i = 0; i < 4; ++i)
#pragma unroll
    for (int j = 0; j < 8; ++j) acc[i][j] = 0.f;

  for (int k0 = 0; k0 < K; k0 += GT_K) {
    float4 av = make_float4(0.f, 0.f, 0.f, 0.f);
    if (m0 + ar < M) av = *(const float4*)(A + (size_t)(m0 + ar) * K + k0 + ak);
    As[ak + 0][ar] = av.x;
    As[ak + 1][ar] = av.y;
    As[ak + 2][ar] = av.z;
    As[ak + 3][ar] = av.w;
#pragma unroll
    for (int h = 0; h < 2; ++h) {
      int kk = bk + h * 8;
      *(float4*)&Bs[kk][bc] = *(const float4*)(B + (size_t)(k0 + kk) * N + n0 + bc);
    }
    __syncthreads();
#pragma unroll
    for (int k = 0; k < GT_K; ++k) {
      float4 a  = *(float4*)&As[k][ty * 4];
      float4 b0 = *(float4*)&Bs[k][tx * 8];
      float4 b1 = *(float4*)&Bs[k][tx * 8 + 4];
      float aa[4] = {a.x, a.y, a.z, a.w};
      float bb[8] = {b0.x, b0.y, b0.z, b0.w, b1.x, b1.y, b1.z, b1.w};
#pragma unroll
      for (int i = 0; i < 4; ++i)
#pragma unroll
        for (int j = 0; j < 8; ++j) acc[i][j] = fmaf(aa[i], bb[j], acc[i][j]);
    }
    __syncthreads();
  }

  float* Cout;
  int ldc, nc0;
  if (n0 < split) { Cout = C0; ldc = split; nc0 = n0; }
  else            { Cout = C1; ldc = N - split; nc0 = n0 - split; }
#pragma unroll
  for (int i = 0; i < 4; ++i) {
    size_t r = (size_t)(m0 + ty * 4 + i);
    float4 v0 = make_float4(acc[i][0], acc[i][1], acc[i][2], acc[i][3]);
    float4 v1 = make_float4(acc[i][4], acc[i][5], acc[i][6], acc[i][7]);
    *(float4*)(Cout + r * ldc + nc0 + tx * 8)     = v0;
    *(float4*)(Cout + r * ldc + nc0 + tx * 8 + 4) = v1;
  }
}

// ---------------------------------------------------------------- propagation (width 128)
// One wave per destination node; lane holds 2 channels. out = relu(bn(agg + b [+ res]))

static __global__ __launch_bounds__(256)
void prop128_kernel(const float* __restrict__ Hsrc, int ldh,
                    const int* __restrict__ start, const int* __restrict__ cnt,
                    const int* __restrict__ src_s, const float* __restrict__ norm_s,
                    const float* __restrict__ dis,
                    const float* __restrict__ bvec,
                    const float* __restrict__ g, const float* __restrict__ be,
                    const float* __restrict__ mean, const float* __restrict__ var,
                    const float* __restrict__ res,
                    float* __restrict__ Out, int N) {
  int w = (int)((blockIdx.x * blockDim.x + threadIdx.x) >> 6);
  int lane = threadIdx.x & 63;
  if (w >= N) return;
  int c0 = lane * 2;
  float d = dis[w];
  float d2 = d * d;
  float2 hv = *(const float2*)(Hsrc + (size_t)w * ldh + c0);
  float acc0 = d2 * hv.x, acc1 = d2 * hv.y;
  int s = start[w], n = cnt[w];
  for (int k = 0; k < n; ++k) {
    int src = src_s[s + k];
    float wt = norm_s[s + k];
    float2 v = *(const float2*)(Hsrc + (size_t)src * ldh + c0);
    acc0 = fmaf(wt, v.x, acc0);
    acc1 = fmaf(wt, v.y, acc1);
  }
  float x0 = acc0 + bvec[c0];
  float x1 = acc1 + bvec[c0 + 1];
  if (res) {
    x0 += res[(size_t)w * 128 + c0];
    x1 += res[(size_t)w * 128 + c0 + 1];
  }
  float s0 = g[c0] * rsqrtf(var[c0] + BN_EPS);
  float s1 = g[c0 + 1] * rsqrtf(var[c0 + 1] + BN_EPS);
  x0 = (x0 - mean[c0]) * s0 + be[c0];
  x1 = (x1 - mean[c0 + 1]) * s1 + be[c0 + 1];
  Out[(size_t)w * 128 + c0]     = fmaxf(x0, 0.f);
  Out[(size_t)w * 128 + c0 + 1] = fmaxf(x1, 0.f);
}

// ---------------------------------------------------------------- h2 @ W3 (dot per node)

static __global__ __launch_bounds__(256)
void w3_kernel(const float* __restrict__ Hin, const float* __restrict__ W3,
               float* __restrict__ h3, int N) {
  int w = (int)((blockIdx.x * blockDim.x + threadIdx.x) >> 6);
  int lane = threadIdx.x & 63;
  if (w >= N) return;
  float v = Hin[(size_t)w * 128 + lane] * W3[lane]
          + Hin[(size_t)w * 128 + 64 + lane] * W3[64 + lane];
#pragma unroll
  for (int off = 32; off > 0; off >>= 1) v += __shfl_down(v, off, 64);
  if (lane == 0) h3[w] = v;
}

// ---------------------------------------------------------------- final 1-wide propagation

static __global__ void prop3_kernel(const float* __restrict__ h3,
                                    const int* __restrict__ start, const int* __restrict__ cnt,
                                    const int* __restrict__ src_s, const float* __restrict__ norm_s,
                                    const float* __restrict__ dis, const float* __restrict__ b3,
                                    float* __restrict__ out, int N) {
  int i = blockIdx.x * blockDim.x + threadIdx.x;
  if (i >= N) return;
  float d = dis[i];
  float acc = d * d * h3[i];
  int s = start[i], n = cnt[i];
  for (int k = 0; k < n; ++k)
    acc = fmaf(norm_s[s + k], h3[src_s[s + k]], acc);
  out[i] = acc + b3[0];
}

// ---------------------------------------------------------------- launch

extern "C" void kernel_launch(void* const* d_in, const int* in_sizes, int n_in,
                              void* d_out, int out_size, void* d_ws, size_t ws_size,
                              hipStream_t stream) {
  const float* x    = (const float*)d_in[0];
  const int*   ei   = (const int*)d_in[1];
  const float* ew   = (const float*)d_in[2];
  const float* W1   = (const float*)d_in[3];
  const float* b1   = (const float*)d_in[4];
  const float* W2   = (const float*)d_in[5];
  const float* b2   = (const float*)d_in[6];
  const float* W3   = (const float*)d_in[7];
  const float* b3   = (const float*)d_in[8];
  const float* Wres = (const float*)d_in[9];
  const float* g1   = (const float*)d_in[10];
  const float* be1  = (const float*)d_in[11];
  const float* m1   = (const float*)d_in[12];
  const float* v1   = (const float*)d_in[13];
  const float* g2   = (const float*)d_in[14];
  const float* be2  = (const float*)d_in[15];
  const float* m2   = (const float*)d_in[16];
  const float* v2   = (const float*)d_in[17];

  int Hh = in_sizes[4];            // 128
  int V  = in_sizes[3] / Hh;       // 256
  int N  = in_sizes[0] / V;        // 100000
  int E  = in_sizes[2];            // 1600000
  const int* row = ei;
  const int* col = ei + E;

  int Mp = ((N + GT_M - 1) / GT_M) * GT_M;

  char* p = (char*)d_ws;
  auto alloc = [&](size_t bytes) -> char* {
    char* r = p;
    p += (bytes + 255) & ~(size_t)255;
    return r;
  };
  float* deg    = (float*)alloc((size_t)N * 4);   // becomes dis in place
  int*   cnt    = (int*)  alloc((size_t)N * 4);
  int*   startA = (int*)  alloc((size_t)N * 4);
  int*   cursor = (int*)  alloc((size_t)N * 4);
  int*   blkSum = (int*)  alloc(256 * 4);
  int*   blkOff = (int*)  alloc(256 * 4);
  int*   src_s  = (int*)  alloc((size_t)E * 4);
  float* norm_s = (float*)alloc((size_t)E * 4);
  float* h3     = (float*)alloc((size_t)N * 4);
  float* Wcat   = (float*)alloc((size_t)V * 2 * Hh * 4);
  float* bufXW1 = (float*)alloc((size_t)Mp * Hh * 4);  // x@W1, later h1@W2
  float* bufRes = (float*)alloc((size_t)Mp * Hh * 4);  // x@Wres
  float* bufH1  = (float*)alloc((size_t)Mp * Hh * 4);  // h1, later h2
  (void)ws_size; (void)n_in; (void)out_size;

  int TB = 256;
  init_deg_cnt<<<(N + TB - 1) / TB, TB, 0, stream>>>(deg, cnt, N);
  hist_kernel<<<(E + TB - 1) / TB, TB, 0, stream>>>(col, ew, deg, cnt, E);
  dis_kernel<<<(N + TB - 1) / TB, TB, 0, stream>>>(deg, N);

  int nb = (N + SCAN_B * SCAN_I - 1) / (SCAN_B * SCAN_I);
  scanA<<<nb, SCAN_B, 0, stream>>>(cnt, startA, blkSum, N);
  scanB<<<1, 256, 0, stream>>>(blkSum, blkOff, nb);
  scanC<<<(N + TB - 1) / TB, TB, 0, stream>>>(startA, cursor, blkOff, N);
  scatter_kernel<<<(E + TB - 1) / TB, TB, 0, stream>>>(row, col, ew, deg, cursor,
                                                       src_s, norm_s, E);

  pack_w<<<(V * 2 * Hh + TB - 1) / TB, TB, 0, stream>>>(W1, Wres, Wcat, V, Hh);

  // GEMM1: x @ [W1|Wres] -> bufXW1 (cols<128), bufRes (cols>=128)
  dim3 gg1(Mp / GT_M, (2 * Hh) / GT_N);
  gemm_kernel<<<gg1, 256, 0, stream>>>(x, Wcat, bufXW1, bufRes, N, 2 * Hh, V, Hh);

  // prop1: h1 = relu(bn1(agg(xW1) + b1)) -> bufH1
  int propBlocks = (int)(((size_t)N * 64 + TB - 1) / TB);
  prop128_kernel<<<propBlocks, TB, 0, stream>>>(bufXW1, Hh, startA, cnt, src_s, norm_s,
                                                deg, b1, g1, be1, m1, v1, nullptr,
                                                bufH1, N);

  // GEMM2: h1 @ W2 -> bufXW1 (reused)
  dim3 gg2(Mp / GT_M, Hh / GT_N);
  gemm_kernel<<<gg2, 256, 0, stream>>>(bufH1, W2, bufXW1, nullptr, N, Hh, Hh, Hh);

  // prop2: h2 = relu(bn2(agg(h1W2) + b2 + res)) -> bufH1 (reused)
  prop128_kernel<<<propBlocks, TB, 0, stream>>>(bufXW1, Hh, startA, cnt, src_s, norm_s,
                                                deg, b2, g2, be2, m2, v2, bufRes,
                                                bufH1, N);

  // h3 = h2 @ W3
  w3_kernel<<<propBlocks, TB, 0, stream>>>(bufH1, W3, h3, N);

  // out = agg(h3) + b3
  prop3_kernel<<<(N + TB - 1) / TB, TB, 0, stream>>>(h3, startA, cnt, src_s, norm_s,
                                                     deg, b3, (float*)d_out, N);
}

// Round 3
// 816.772 us; speedup vs baseline: 1.2629x; 1.2629x over previous
//
#include <hip/hip_runtime.h>
#include <hip/hip_bf16.h>

#define BN_EPS 1e-5f

static __device__ __forceinline__ unsigned short f2bf(float f) {
  unsigned int u = __float_as_uint(f);
  unsigned int r = (u + 0x7fffu + ((u >> 16) & 1u)) >> 16;
  return (unsigned short)r;
}

// ---------------------------------------------------------------- graph prep

static __global__ void init_deg_cnt(float* deg, int* cnt, int N) {
  int i = blockIdx.x * blockDim.x + threadIdx.x;
  if (i < N) { deg[i] = 1.0f; cnt[i] = 0; }  // self-loop weight 1.0
}

static __global__ void hist_kernel(const int* __restrict__ col,
                                   const float* __restrict__ ew,
                                   float* deg, int* cnt, int E) {
  int e = blockIdx.x * blockDim.x + threadIdx.x;
  if (e < E) {
    int c = col[e];
    atomicAdd(&deg[c], ew[e]);
    atomicAdd(&cnt[c], 1);
  }
}

static __global__ void dis_kernel(float* deg, int N) {
  int i = blockIdx.x * blockDim.x + threadIdx.x;
  if (i < N) {
    float d = deg[i];
    deg[i] = d > 0.f ? rsqrtf(fmaxf(d, 1e-30f)) : 0.f;  // in-place: deg -> dis
  }
}

#define SCAN_B 256
#define SCAN_I 4
static __global__ void scanA(const int* __restrict__ cnt, int* __restrict__ start,
                             int* __restrict__ blkSum, int N) {
  __shared__ int sh[SCAN_B];
  int t = threadIdx.x;
  int base = blockIdx.x * SCAN_B * SCAN_I + t * SCAN_I;
  int v[SCAN_I];
  int tot = 0;
#pragma unroll
  for (int j = 0; j < SCAN_I; ++j) {
    v[j] = (base + j < N) ? cnt[base + j] : 0;
    tot += v[j];
  }
  sh[t] = tot;
  __syncthreads();
  int self = tot;
  for (int off = 1; off < SCAN_B; off <<= 1) {
    int add = (t >= off) ? sh[t - off] : 0;
    __syncthreads();
    sh[t] += add;
    __syncthreads();
  }
  int excl = sh[t] - self;
  if (t == SCAN_B - 1) blkSum[blockIdx.x] = sh[t];
  int run = excl;
#pragma unroll
  for (int j = 0; j < SCAN_I; ++j) {
    if (base + j < N) start[base + j] = run;
    run += v[j];
  }
}

static __global__ void scanB(const int* __restrict__ blkSum, int* __restrict__ blkOff, int nb) {
  __shared__ int sh[256];
  int t = threadIdx.x;
  int v = (t < nb) ? blkSum[t] : 0;
  sh[t] = v;
  __syncthreads();
  for (int off = 1; off < 256; off <<= 1) {
    int add = (t >= off) ? sh[t - off] : 0;
    __syncthreads();
    sh[t] += add;
    __syncthreads();
  }
  if (t < nb) blkOff[t] = sh[t] - v;
}

static __global__ void scanC(int* start, int* cursor, const int* __restrict__ blkOff, int N) {
  int i = blockIdx.x * blockDim.x + threadIdx.x;
  if (i < N) {
    int s = start[i] + blkOff[i / (SCAN_B * SCAN_I)];
    start[i] = s;
    cursor[i] = s;
  }
}

static __global__ void scatter_kernel(const int* __restrict__ row, const int* __restrict__ col,
                                      const float* __restrict__ ew, const float* __restrict__ dis,
                                      int* cursor, int* __restrict__ src_s,
                                      float* __restrict__ norm_s, int E) {
  int e = blockIdx.x * blockDim.x + threadIdx.x;
  if (e < E) {
    int r = row[e], c = col[e];
    int pos = atomicAdd(&cursor[c], 1);
    src_s[pos] = r;
    norm_s[pos] = dis[r] * ew[e] * dis[c];
  }
}

// ---------------------------------------------------------------- pack [W1|Wres]

static __global__ void pack_w(const float* __restrict__ W1, const float* __restrict__ Wres,
                              float* __restrict__ Wcat, int K, int H) {
  int i = blockIdx.x * blockDim.x + threadIdx.x;
  int total = K * 2 * H;
  if (i < total) {
    int k = i / (2 * H), j = i % (2 * H);
    Wcat[i] = (j < H) ? W1[k * H + j] : Wres[k * H + (j - H)];
  }
}

// ---------------------------------------------------------------- fp32 GEMM
// C = A[MxK] * B[KxN]; cols < split -> C0 (bf16, ld=split elements),
// cols >= split -> C1 (fp32, ld=N-split). Tile 64x128, 256 threads, 4x8/thread.

#define GT_M 64
#define GT_N 128
#define GT_K 16

static __global__ __launch_bounds__(256)
void gemm_kernel(const float* __restrict__ A, const float* __restrict__ B,
                 unsigned short* __restrict__ C0b, float* __restrict__ C1,
                 int M, int N, int K, int split) {
  __shared__ float As[GT_K][GT_M + 4];
  __shared__ float Bs[GT_K][GT_N];
  int t = threadIdx.x;
  int m0 = blockIdx.x * GT_M;
  int n0 = blockIdx.y * GT_N;
  int tx = t & 15, ty = t >> 4;
  int ar = t >> 2;          // 0..63 row in tile
  int ak = (t & 3) << 2;    // 0,4,8,12
  int bk = t >> 5;          // 0..7
  int bc = (t & 31) << 2;   // 0..124

  float acc[4][8];
#pragma unroll
  for (int i = 0; i < 4; ++i)
#pragma unroll
    for (int j = 0; j < 8; ++j) acc[i][j] = 0.f;

  for (int k0 = 0; k0 < K; k0 += GT_K) {
    float4 av = make_float4(0.f, 0.f, 0.f, 0.f);
    if (m0 + ar < M) av = *(const float4*)(A + (size_t)(m0 + ar) * K + k0 + ak);
    As[ak + 0][ar] = av.x;
    As[ak + 1][ar] = av.y;
    As[ak + 2][ar] = av.z;
    As[ak + 3][ar] = av.w;
#pragma unroll
    for (int h = 0; h < 2; ++h) {
      int kk = bk + h * 8;
      *(float4*)&Bs[kk][bc] = *(const float4*)(B + (size_t)(k0 + kk) * N + n0 + bc);
    }
    __syncthreads();
#pragma unroll
    for (int k = 0; k < GT_K; ++k) {
      float4 a  = *(float4*)&As[k][ty * 4];
      float4 b0 = *(float4*)&Bs[k][tx * 8];
      float4 b1 = *(float4*)&Bs[k][tx * 8 + 4];
      float aa[4] = {a.x, a.y, a.z, a.w};
      float bb[8] = {b0.x, b0.y, b0.z, b0.w, b1.x, b1.y, b1.z, b1.w};
#pragma unroll
      for (int i = 0; i < 4; ++i)
#pragma unroll
        for (int j = 0; j < 8; ++j) acc[i][j] = fmaf(aa[i], bb[j], acc[i][j]);
    }
    __syncthreads();
  }

  if (n0 < split) {
    // bf16 output (consumed by gather-propagation)
#pragma unroll
    for (int i = 0; i < 4; ++i) {
      size_t r = (size_t)(m0 + ty * 4 + i);
      ushort4 lo, hi;
      lo.x = f2bf(acc[i][0]); lo.y = f2bf(acc[i][1]);
      lo.z = f2bf(acc[i][2]); lo.w = f2bf(acc[i][3]);
      hi.x = f2bf(acc[i][4]); hi.y = f2bf(acc[i][5]);
      hi.z = f2bf(acc[i][6]); hi.w = f2bf(acc[i][7]);
      *(ushort4*)(C0b + r * split + n0 + tx * 8)     = lo;
      *(ushort4*)(C0b + r * split + n0 + tx * 8 + 4) = hi;
    }
  } else {
    int ldc = N - split, nc0 = n0 - split;
#pragma unroll
    for (int i = 0; i < 4; ++i) {
      size_t r = (size_t)(m0 + ty * 4 + i);
      float4 v0 = make_float4(acc[i][0], acc[i][1], acc[i][2], acc[i][3]);
      float4 v1 = make_float4(acc[i][4], acc[i][5], acc[i][6], acc[i][7]);
      *(float4*)(C1 + r * ldc + nc0 + tx * 8)     = v0;
      *(float4*)(C1 + r * ldc + nc0 + tx * 8 + 4) = v1;
    }
  }
}

// ---------------------------------------------------------------- propagation (width 128)
// One wave per destination node; lane holds 2 channels (one bf16x2 word).
// Edge indices/weights are lane-parallel loaded then shfl-broadcast; gathers
// issued in unrolled groups of 8 independent loads (MLP). out = relu(bn(...)).

static __global__ __launch_bounds__(256)
void prop128_kernel(const unsigned int* __restrict__ Hsrc,  // N x 64 bf16x2 words
                    const int* __restrict__ start, const int* __restrict__ cnt,
                    const int* __restrict__ src_s, const float* __restrict__ norm_s,
                    const float* __restrict__ dis,
                    const float* __restrict__ bvec,
                    const float* __restrict__ g, const float* __restrict__ be,
                    const float* __restrict__ mean, const float* __restrict__ var,
                    const float* __restrict__ res,
                    float* __restrict__ Out, int N) {
  int w = (int)((blockIdx.x * blockDim.x + threadIdx.x) >> 6);
  int lane = threadIdx.x & 63;
  if (w >= N) return;
  int c0 = lane * 2;
  float d = dis[w];
  float d2 = d * d;

  float acc0, acc1;
  {
    unsigned int u = Hsrc[(size_t)w * 64 + lane];
    acc0 = d2 * __uint_as_float(u << 16);
    acc1 = d2 * __uint_as_float(u & 0xffff0000u);
  }

  int s = start[w], n = cnt[w];
  int k = 0;
  while (k < n) {
    int chunk = min(n - k, 64);
    int idx = 0;
    float wt = 0.f;
    if (lane < chunk) {
      idx = src_s[s + k + lane];
      wt  = norm_s[s + k + lane];
    }
    // groups of 8; lanes >= chunk contribute idx=0, wt=0 (harmless hot row)
    for (int j = 0; j < chunk; j += 8) {
      int   i0 = __shfl(idx, j + 0, 64), i1 = __shfl(idx, j + 1, 64);
      int   i2 = __shfl(idx, j + 2, 64), i3 = __shfl(idx, j + 3, 64);
      int   i4 = __shfl(idx, j + 4, 64), i5 = __shfl(idx, j + 5, 64);
      int   i6 = __shfl(idx, j + 6, 64), i7 = __shfl(idx, j + 7, 64);
      float w0 = __shfl(wt, j + 0, 64), w1 = __shfl(wt, j + 1, 64);
      float w2 = __shfl(wt, j + 2, 64), w3 = __shfl(wt, j + 3, 64);
      float w4 = __shfl(wt, j + 4, 64), w5 = __shfl(wt, j + 5, 64);
      float w6 = __shfl(wt, j + 6, 64), w7 = __shfl(wt, j + 7, 64);
      unsigned int u0 = Hsrc[(size_t)i0 * 64 + lane];
      unsigned int u1 = Hsrc[(size_t)i1 * 64 + lane];
      unsigned int u2 = Hsrc[(size_t)i2 * 64 + lane];
      unsigned int u3 = Hsrc[(size_t)i3 * 64 + lane];
      unsigned int u4 = Hsrc[(size_t)i4 * 64 + lane];
      unsigned int u5 = Hsrc[(size_t)i5 * 64 + lane];
      unsigned int u6 = Hsrc[(size_t)i6 * 64 + lane];
      unsigned int u7 = Hsrc[(size_t)i7 * 64 + lane];
      acc0 = fmaf(w0, __uint_as_float(u0 << 16), acc0);
      acc1 = fmaf(w0, __uint_as_float(u0 & 0xffff0000u), acc1);
      acc0 = fmaf(w1, __uint_as_float(u1 << 16), acc0);
      acc1 = fmaf(w1, __uint_as_float(u1 & 0xffff0000u), acc1);
      acc0 = fmaf(w2, __uint_as_float(u2 << 16), acc0);
      acc1 = fmaf(w2, __uint_as_float(u2 & 0xffff0000u), acc1);
      acc0 = fmaf(w3, __uint_as_float(u3 << 16), acc0);
      acc1 = fmaf(w3, __uint_as_float(u3 & 0xffff0000u), acc1);
      acc0 = fmaf(w4, __uint_as_float(u4 << 16), acc0);
      acc1 = fmaf(w4, __uint_as_float(u4 & 0xffff0000u), acc1);
      acc0 = fmaf(w5, __uint_as_float(u5 << 16), acc0);
      acc1 = fmaf(w5, __uint_as_float(u5 & 0xffff0000u), acc1);
      acc0 = fmaf(w6, __uint_as_float(u6 << 16), acc0);
      acc1 = fmaf(w6, __uint_as_float(u6 & 0xffff0000u), acc1);
      acc0 = fmaf(w7, __uint_as_float(u7 << 16), acc0);
      acc1 = fmaf(w7, __uint_as_float(u7 & 0xffff0000u), acc1);
    }
    k += chunk;
  }

  float x0 = acc0 + bvec[c0];
  float x1 = acc1 + bvec[c0 + 1];
  if (res) {
    x0 += res[(size_t)w * 128 + c0];
    x1 += res[(size_t)w * 128 + c0 + 1];
  }
  float s0 = g[c0] * rsqrtf(var[c0] + BN_EPS);
  float s1 = g[c0 + 1] * rsqrtf(var[c0 + 1] + BN_EPS);
  x0 = (x0 - mean[c0]) * s0 + be[c0];
  x1 = (x1 - mean[c0 + 1]) * s1 + be[c0 + 1];
  Out[(size_t)w * 128 + c0]     = fmaxf(x0, 0.f);
  Out[(size_t)w * 128 + c0 + 1] = fmaxf(x1, 0.f);
}

// ---------------------------------------------------------------- h2 @ W3 (dot per node)

static __global__ __launch_bounds__(256)
void w3_kernel(const float* __restrict__ Hin, const float* __restrict__ W3,
               float* __restrict__ h3, int N) {
  int w = (int)((blockIdx.x * blockDim.x + threadIdx.x) >> 6);
  int lane = threadIdx.x & 63;
  if (w >= N) return;
  float v = Hin[(size_t)w * 128 + lane] * W3[lane]
          + Hin[(size_t)w * 128 + 64 + lane] * W3[64 + lane];
#pragma unroll
  for (int off = 32; off > 0; off >>= 1) v += __shfl_down(v, off, 64);
  if (lane == 0) h3[w] = v;
}

// ---------------------------------------------------------------- final 1-wide propagation

static __global__ void prop3_kernel(const float* __restrict__ h3,
                                    const int* __restrict__ start, const int* __restrict__ cnt,
                                    const int* __restrict__ src_s, const float* __restrict__ norm_s,
                                    const float* __restrict__ dis, const float* __restrict__ b3,
                                    float* __restrict__ out, int N) {
  int i = blockIdx.x * blockDim.x + threadIdx.x;
  if (i >= N) return;
  float d = dis[i];
  float acc = d * d * h3[i];
  int s = start[i], n = cnt[i];
  for (int k = 0; k < n; ++k)
    acc = fmaf(norm_s[s + k], h3[src_s[s + k]], acc);
  out[i] = acc + b3[0];
}

// ---------------------------------------------------------------- launch

extern "C" void kernel_launch(void* const* d_in, const int* in_sizes, int n_in,
                              void* d_out, int out_size, void* d_ws, size_t ws_size,
                              hipStream_t stream) {
  const float* x    = (const float*)d_in[0];
  const int*   ei   = (const int*)d_in[1];
  const float* ew   = (const float*)d_in[2];
  const float* W1   = (const float*)d_in[3];
  const float* b1   = (const float*)d_in[4];
  const float* W2   = (const float*)d_in[5];
  const float* b2   = (const float*)d_in[6];
  const float* W3   = (const float*)d_in[7];
  const float* b3   = (const float*)d_in[8];
  const float* Wres = (const float*)d_in[9];
  const float* g1   = (const float*)d_in[10];
  const float* be1  = (const float*)d_in[11];
  const float* m1   = (const float*)d_in[12];
  const float* v1   = (const float*)d_in[13];
  const float* g2   = (const float*)d_in[14];
  const float* be2  = (const float*)d_in[15];
  const float* m2   = (const float*)d_in[16];
  const float* v2   = (const float*)d_in[17];

  int Hh = in_sizes[4];            // 128
  int V  = in_sizes[3] / Hh;       // 256
  int N  = in_sizes[0] / V;        // 100000
  int E  = in_sizes[2];            // 1600000
  const int* row = ei;
  const int* col = ei + E;

  int Mp = ((N + GT_M - 1) / GT_M) * GT_M;

  char* p = (char*)d_ws;
  auto alloc = [&](size_t bytes) -> char* {
    char* r = p;
    p += (bytes + 255) & ~(size_t)255;
    return r;
  };
  float* deg    = (float*)alloc((size_t)N * 4);   // becomes dis in place
  int*   cnt    = (int*)  alloc((size_t)N * 4);
  int*   startA = (int*)  alloc((size_t)N * 4);
  int*   cursor = (int*)  alloc((size_t)N * 4);
  int*   blkSum = (int*)  alloc(256 * 4);
  int*   blkOff = (int*)  alloc(256 * 4);
  int*   src_s  = (int*)  alloc((size_t)E * 4);
  float* norm_s = (float*)alloc((size_t)E * 4);
  float* h3     = (float*)alloc((size_t)N * 4);
  float* Wcat   = (float*)alloc((size_t)V * 2 * Hh * 4);
  unsigned short* bufG = (unsigned short*)alloc((size_t)Mp * Hh * 2);  // bf16 gather buf
  float* bufRes = (float*)alloc((size_t)Mp * Hh * 4);  // x@Wres fp32
  float* bufH1  = (float*)alloc((size_t)Mp * Hh * 4);  // h1 fp32, later h2
  (void)ws_size; (void)n_in; (void)out_size;

  int TB = 256;
  init_deg_cnt<<<(N + TB - 1) / TB, TB, 0, stream>>>(deg, cnt, N);
  hist_kernel<<<(E + TB - 1) / TB, TB, 0, stream>>>(col, ew, deg, cnt, E);
  dis_kernel<<<(N + TB - 1) / TB, TB, 0, stream>>>(deg, N);

  int nb = (N + SCAN_B * SCAN_I - 1) / (SCAN_B * SCAN_I);
  scanA<<<nb, SCAN_B, 0, stream>>>(cnt, startA, blkSum, N);
  scanB<<<1, 256, 0, stream>>>(blkSum, blkOff, nb);
  scanC<<<(N + TB - 1) / TB, TB, 0, stream>>>(startA, cursor, blkOff, N);
  scatter_kernel<<<(E + TB - 1) / TB, TB, 0, stream>>>(row, col, ew, deg, cursor,
                                                       src_s, norm_s, E);

  pack_w<<<(V * 2 * Hh + TB - 1) / TB, TB, 0, stream>>>(W1, Wres, Wcat, V, Hh);

  // GEMM1: x @ [W1|Wres] -> bufG (bf16, cols<128), bufRes (fp32, cols>=128)
  dim3 gg1(Mp / GT_M, (2 * Hh) / GT_N);
  gemm_kernel<<<gg1, 256, 0, stream>>>(x, Wcat, bufG, bufRes, N, 2 * Hh, V, Hh);

  // prop1: h1 = relu(bn1(agg(xW1) + b1)) -> bufH1 (fp32)
  int propBlocks = (int)(((size_t)N * 64 + TB - 1) / TB);
  prop128_kernel<<<propBlocks, TB, 0, stream>>>((const unsigned int*)bufG, startA, cnt,
                                                src_s, norm_s, deg, b1, g1, be1, m1, v1,
                                                nullptr, bufH1, N);

  // GEMM2: h1 @ W2 -> bufG (bf16, reused)
  dim3 gg2(Mp / GT_M, Hh / GT_N);
  gemm_kernel<<<gg2, 256, 0, stream>>>(bufH1, W2, bufG, nullptr, N, Hh, Hh, Hh);

  // prop2: h2 = relu(bn2(agg(h1W2) + b2 + res)) -> bufH1 (reused)
  prop128_kernel<<<propBlocks, TB, 0, stream>>>((const unsigned int*)bufG, startA, cnt,
                                                src_s, norm_s, deg, b2, g2, be2, m2, v2,
                                                bufRes, bufH1, N);

  // h3 = h2 @ W3
  w3_kernel<<<propBlocks, TB, 0, stream>>>(bufH1, W3, h3, N);

  // out = agg(h3) + b3
  prop3_kernel<<<(N + TB - 1) / TB, TB, 0, stream>>>(h3, startA, cnt, src_s, norm_s,
                                                     deg, b3, (float*)d_out, N);
}

// Round 4
// 656.145 us; speedup vs baseline: 1.5721x; 1.2448x over previous
//
#include <hip/hip_runtime.h>
#include <hip/hip_bf16.h>

#define BN_EPS 1e-5f

using short8 = __attribute__((ext_vector_type(8))) short;
using f32x4  = __attribute__((ext_vector_type(4))) float;

static __device__ __forceinline__ unsigned short f2bf(float f) {
  unsigned int u = __float_as_uint(f);
  unsigned int r = (u + 0x7fffu + ((u >> 16) & 1u)) >> 16;
  return (unsigned short)r;
}

// ---------------------------------------------------------------- graph prep

static __global__ void init_deg_cnt(float* deg, int* cnt, int N) {
  int i = blockIdx.x * blockDim.x + threadIdx.x;
  if (i < N) { deg[i] = 1.0f; cnt[i] = 0; }  // self-loop weight 1.0
}

static __global__ void hist_kernel(const int* __restrict__ col,
                                   const float* __restrict__ ew,
                                   float* deg, int* cnt, int E) {
  int e = blockIdx.x * blockDim.x + threadIdx.x;
  if (e < E) {
    int c = col[e];
    atomicAdd(&deg[c], ew[e]);
    atomicAdd(&cnt[c], 1);
  }
}

static __global__ void dis_kernel(float* deg, int N) {
  int i = blockIdx.x * blockDim.x + threadIdx.x;
  if (i < N) {
    float d = deg[i];
    deg[i] = d > 0.f ? rsqrtf(fmaxf(d, 1e-30f)) : 0.f;  // in-place: deg -> dis
  }
}

#define SCAN_B 256
#define SCAN_I 4
static __global__ void scanA(const int* __restrict__ cnt, int* __restrict__ start,
                             int* __restrict__ blkSum, int N) {
  __shared__ int sh[SCAN_B];
  int t = threadIdx.x;
  int base = blockIdx.x * SCAN_B * SCAN_I + t * SCAN_I;
  int v[SCAN_I];
  int tot = 0;
#pragma unroll
  for (int j = 0; j < SCAN_I; ++j) {
    v[j] = (base + j < N) ? cnt[base + j] : 0;
    tot += v[j];
  }
  sh[t] = tot;
  __syncthreads();
  int self = tot;
  for (int off = 1; off < SCAN_B; off <<= 1) {
    int add = (t >= off) ? sh[t - off] : 0;
    __syncthreads();
    sh[t] += add;
    __syncthreads();
  }
  int excl = sh[t] - self;
  if (t == SCAN_B - 1) blkSum[blockIdx.x] = sh[t];
  int run = excl;
#pragma unroll
  for (int j = 0; j < SCAN_I; ++j) {
    if (base + j < N) start[base + j] = run;
    run += v[j];
  }
}

static __global__ void scanB(const int* __restrict__ blkSum, int* __restrict__ blkOff, int nb) {
  __shared__ int sh[256];
  int t = threadIdx.x;
  int v = (t < nb) ? blkSum[t] : 0;
  sh[t] = v;
  __syncthreads();
  for (int off = 1; off < 256; off <<= 1) {
    int add = (t >= off) ? sh[t - off] : 0;
    __syncthreads();
    sh[t] += add;
    __syncthreads();
  }
  if (t < nb) blkOff[t] = sh[t] - v;
}

static __global__ void scanC(int* start, int* cursor, const int* __restrict__ blkOff, int N) {
  int i = blockIdx.x * blockDim.x + threadIdx.x;
  if (i < N) {
    int s = start[i] + blkOff[i / (SCAN_B * SCAN_I)];
    start[i] = s;
    cursor[i] = s;
  }
}

static __global__ void scatter_kernel(const int* __restrict__ row, const int* __restrict__ col,
                                      const float* __restrict__ ew, const float* __restrict__ dis,
                                      int* cursor, int* __restrict__ src_s,
                                      float* __restrict__ norm_s, int E) {
  int e = blockIdx.x * blockDim.x + threadIdx.x;
  if (e < E) {
    int r = row[e], c = col[e];
    int pos = atomicAdd(&cursor[c], 1);
    src_s[pos] = r;
    norm_s[pos] = dis[r] * ew[e] * dis[c];
  }
}

// ------------------------------------------------- weight cast (bf16, n-major)
// BT1[n][k] = n<128 ? W1[k][n] : Wres[k][n-128]   (256 x 256)
// BT2[n][k] = W2[k][n]                            (128 x 128)

static __global__ void cast_weights(const float* __restrict__ W1, const float* __restrict__ Wres,
                                    const float* __restrict__ W2,
                                    unsigned short* __restrict__ BT1,
                                    unsigned short* __restrict__ BT2) {
  int i = blockIdx.x * blockDim.x + threadIdx.x;
  if (i < 256 * 256) {
    int n = i >> 8, k = i & 255;
    float v = (n < 128) ? W1[k * 128 + n] : Wres[k * 128 + (n - 128)];
    BT1[i] = f2bf(v);
  } else if (i < 256 * 256 + 128 * 128) {
    int j = i - 256 * 256;
    int n = j >> 7, k = j & 127;
    BT2[j] = f2bf(W2[k * 128 + n]);
  }
}

// ---------------------------------------------------------------- GEMM1 (MFMA)
// C[M x 256] = A[M x 256] (fp32, cast to bf16 in staging) @ B[256 x 256]
// B given transposed (BT, n-major). Block: 256 thr (4 waves), tile 64(M) x 256(N),
// each wave owns a 64-wide n-slice. Cols <128 -> C0 bf16; cols >=128 -> C1 fp32.
// LDS rows padded to 40 shorts (80 B) -> 2-way bank aliasing only (free).

static __global__ __launch_bounds__(256)
void gemm1_mfma(const float* __restrict__ A, const unsigned short* __restrict__ BT,
                unsigned short* __restrict__ C0, float* __restrict__ C1, int M) {
  __shared__ unsigned short As[64 * 40];
  __shared__ unsigned short Bs[256 * 40];
  int t = threadIdx.x;
  int wv = t >> 6, lane = t & 63;
  int quad = lane >> 4, l15 = lane & 15;
  int m0 = blockIdx.x * 64;

  f32x4 acc[4][4];
#pragma unroll
  for (int i = 0; i < 4; ++i)
#pragma unroll
    for (int j = 0; j < 4; ++j) acc[i][j] = (f32x4){0.f, 0.f, 0.f, 0.f};

  int ar = t >> 2;          // A-stage row 0..63
  int ac = (t & 3) * 8;     // A-stage k-offset 0,8,16,24
  bool avalid = (m0 + ar) < M;
  const float* Arow = A + (size_t)(m0 + ar) * 256 + ac;
  const unsigned short* Brow = BT + (size_t)t * 256;  // t = B row (n) 0..255

  for (int k0 = 0; k0 < 256; k0 += 32) {
    float4 a0 = make_float4(0.f, 0.f, 0.f, 0.f), a1 = a0;
    if (avalid) {
      a0 = *(const float4*)(Arow + k0);
      a1 = *(const float4*)(Arow + k0 + 4);
    }
    short8 av;
    av[0] = (short)f2bf(a0.x); av[1] = (short)f2bf(a0.y);
    av[2] = (short)f2bf(a0.z); av[3] = (short)f2bf(a0.w);
    av[4] = (short)f2bf(a1.x); av[5] = (short)f2bf(a1.y);
    av[6] = (short)f2bf(a1.z); av[7] = (short)f2bf(a1.w);
    *(short8*)&As[ar * 40 + ac] = av;

    short8 b0 = *(const short8*)(Brow + k0);
    short8 b1 = *(const short8*)(Brow + k0 + 8);
    short8 b2 = *(const short8*)(Brow + k0 + 16);
    short8 b3 = *(const short8*)(Brow + k0 + 24);
    *(short8*)&Bs[t * 40 + 0]  = b0;
    *(short8*)&Bs[t * 40 + 8]  = b1;
    *(short8*)&Bs[t * 40 + 16] = b2;
    *(short8*)&Bs[t * 40 + 24] = b3;
    __syncthreads();

    short8 af[4], bf[4];
#pragma unroll
    for (int mt = 0; mt < 4; ++mt)
      af[mt] = *(const short8*)&As[(mt * 16 + l15) * 40 + quad * 8];
#pragma unroll
    for (int nt = 0; nt < 4; ++nt)
      bf[nt] = *(const short8*)&Bs[(wv * 64 + nt * 16 + l15) * 40 + quad * 8];
#pragma unroll
    for (int mt = 0; mt < 4; ++mt)
#pragma unroll
      for (int nt = 0; nt < 4; ++nt)
        acc[mt][nt] = __builtin_amdgcn_mfma_f32_16x16x32_bf16(af[mt], bf[nt], acc[mt][nt], 0, 0, 0);
    __syncthreads();
  }

  // epilogue: D row = quad*4+reg (m), col = l15 (n)
  int nbase = wv * 64;
#pragma unroll
  for (int mt = 0; mt < 4; ++mt) {
#pragma unroll
    for (int nt = 0; nt < 4; ++nt) {
      int n = nbase + nt * 16 + l15;
#pragma unroll
      for (int reg = 0; reg < 4; ++reg) {
        size_t m = (size_t)(m0 + mt * 16 + quad * 4 + reg);
        if (nbase < 128) C0[m * 128 + n] = f2bf(acc[mt][nt][reg]);
        else             C1[m * 128 + (n - 128)] = acc[mt][nt][reg];
      }
    }
  }
}

// ---------------------------------------------------------------- GEMM2 (MFMA)
// C[M x 128] bf16 = A[M x 128] bf16 @ B[128 x 128] (BT n-major bf16).
// Block: 256 thr (4 waves), tile 128 x 128; wave -> (m-half, n-half) 64x64.

static __global__ __launch_bounds__(256)
void gemm2_mfma(const unsigned short* __restrict__ A, const unsigned short* __restrict__ BT,
                unsigned short* __restrict__ C, int Mp) {
  __shared__ unsigned short As[128 * 40];
  __shared__ unsigned short Bs[128 * 40];
  int t = threadIdx.x;
  int wv = t >> 6, lane = t & 63;
  int quad = lane >> 4, l15 = lane & 15;
  int m0 = blockIdx.x * 128;

  f32x4 acc[4][4];
#pragma unroll
  for (int i = 0; i < 4; ++i)
#pragma unroll
    for (int j = 0; j < 4; ++j) acc[i][j] = (f32x4){0.f, 0.f, 0.f, 0.f};

  int sr = t >> 1, sc = (t & 1) * 16;  // stage: row, k-offset

  for (int k0 = 0; k0 < 128; k0 += 32) {
    short8 a0 = *(const short8*)(A + (size_t)(m0 + sr) * 128 + k0 + sc);
    short8 a1 = *(const short8*)(A + (size_t)(m0 + sr) * 128 + k0 + sc + 8);
    *(short8*)&As[sr * 40 + sc]     = a0;
    *(short8*)&As[sr * 40 + sc + 8] = a1;
    short8 b0 = *(const short8*)(BT + (size_t)sr * 128 + k0 + sc);
    short8 b1 = *(const short8*)(BT + (size_t)sr * 128 + k0 + sc + 8);
    *(short8*)&Bs[sr * 40 + sc]     = b0;
    *(short8*)&Bs[sr * 40 + sc + 8] = b1;
    __syncthreads();

    int mb = (wv >> 1) * 64, nb = (wv & 1) * 64;
    short8 af[4], bf[4];
#pragma unroll
    for (int mt = 0; mt < 4; ++mt)
      af[mt] = *(const short8*)&As[(mb + mt * 16 + l15) * 40 + quad * 8];
#pragma unroll
    for (int nt = 0; nt < 4; ++nt)
      bf[nt] = *(const short8*)&Bs[(nb + nt * 16 + l15) * 40 + quad * 8];
#pragma unroll
    for (int mt = 0; mt < 4; ++mt)
#pragma unroll
      for (int nt = 0; nt < 4; ++nt)
        acc[mt][nt] = __builtin_amdgcn_mfma_f32_16x16x32_bf16(af[mt], bf[nt], acc[mt][nt], 0, 0, 0);
    __syncthreads();
  }

  int mb = (wv >> 1) * 64, nb = (wv & 1) * 64;
#pragma unroll
  for (int mt = 0; mt < 4; ++mt)
#pragma unroll
    for (int nt = 0; nt < 4; ++nt) {
      int n = nb + nt * 16 + l15;
#pragma unroll
      for (int reg = 0; reg < 4; ++reg) {
        size_t m = (size_t)(m0 + mb + mt * 16 + quad * 4 + reg);
        C[m * 128 + n] = f2bf(acc[mt][nt][reg]);
      }
    }
  (void)Mp;
}

// ---------------------------------------------------------------- propagation core
// One wave per destination node; lane holds 2 channels (one bf16x2 word).

#define PROP_GATHER_BODY                                                        \
  int c0 = lane * 2;                                                            \
  float d = dis[w];                                                             \
  float d2 = d * d;                                                             \
  float acc0, acc1;                                                             \
  {                                                                             \
    unsigned int u = Hsrc[(size_t)w * 64 + lane];                               \
    acc0 = d2 * __uint_as_float(u << 16);                                       \
    acc1 = d2 * __uint_as_float(u & 0xffff0000u);                               \
  }                                                                             \
  int s = start[w], n = cnt[w];                                                 \
  int k = 0;                                                                    \
  while (k < n) {                                                               \
    int chunk = min(n - k, 64);                                                 \
    int idx = 0;                                                                \
    float wt = 0.f;                                                             \
    if (lane < chunk) {                                                         \
      idx = src_s[s + k + lane];                                                \
      wt  = norm_s[s + k + lane];                                               \
    }                                                                           \
    for (int j = 0; j < chunk; j += 8) {                                        \
      int   i0 = __shfl(idx, j + 0, 64), i1 = __shfl(idx, j + 1, 64);           \
      int   i2 = __shfl(idx, j + 2, 64), i3 = __shfl(idx, j + 3, 64);           \
      int   i4 = __shfl(idx, j + 4, 64), i5 = __shfl(idx, j + 5, 64);           \
      int   i6 = __shfl(idx, j + 6, 64), i7 = __shfl(idx, j + 7, 64);           \
      float w0 = __shfl(wt, j + 0, 64), w1 = __shfl(wt, j + 1, 64);             \
      float w2 = __shfl(wt, j + 2, 64), w3 = __shfl(wt, j + 3, 64);             \
      float w4 = __shfl(wt, j + 4, 64), w5 = __shfl(wt, j + 5, 64);             \
      float w6 = __shfl(wt, j + 6, 64), w7 = __shfl(wt, j + 7, 64);             \
      unsigned int u0 = Hsrc[(size_t)i0 * 64 + lane];                           \
      unsigned int u1 = Hsrc[(size_t)i1 * 64 + lane];                           \
      unsigned int u2 = Hsrc[(size_t)i2 * 64 + lane];                           \
      unsigned int u3 = Hsrc[(size_t)i3 * 64 + lane];                           \
      unsigned int u4 = Hsrc[(size_t)i4 * 64 + lane];                           \
      unsigned int u5 = Hsrc[(size_t)i5 * 64 + lane];                           \
      unsigned int u6 = Hsrc[(size_t)i6 * 64 + lane];                           \
      unsigned int u7 = Hsrc[(size_t)i7 * 64 + lane];                           \
      acc0 = fmaf(w0, __uint_as_float(u0 << 16), acc0);                         \
      acc1 = fmaf(w0, __uint_as_float(u0 & 0xffff0000u), acc1);                 \
      acc0 = fmaf(w1, __uint_as_float(u1 << 16), acc0);                         \
      acc1 = fmaf(w1, __uint_as_float(u1 & 0xffff0000u), acc1);                 \
      acc0 = fmaf(w2, __uint_as_float(u2 << 16), acc0);                         \
      acc1 = fmaf(w2, __uint_as_float(u2 & 0xffff0000u), acc1);                 \
      acc0 = fmaf(w3, __uint_as_float(u3 << 16), acc0);                         \
      acc1 = fmaf(w3, __uint_as_float(u3 & 0xffff0000u), acc1);                 \
      acc0 = fmaf(w4, __uint_as_float(u4 << 16), acc0);                         \
      acc1 = fmaf(w4, __uint_as_float(u4 & 0xffff0000u), acc1);                 \
      acc0 = fmaf(w5, __uint_as_float(u5 << 16), acc0);                         \
      acc1 = fmaf(w5, __uint_as_float(u5 & 0xffff0000u), acc1);                 \
      acc0 = fmaf(w6, __uint_as_float(u6 << 16), acc0);                         \
      acc1 = fmaf(w6, __uint_as_float(u6 & 0xffff0000u), acc1);                 \
      acc0 = fmaf(w7, __uint_as_float(u7 << 16), acc0);                         \
      acc1 = fmaf(w7, __uint_as_float(u7 & 0xffff0000u), acc1);                 \
    }                                                                           \
    k += chunk;                                                                 \
  }

// prop1: h1 = relu(bn1(agg + b1)) -> bf16 packed output
static __global__ __launch_bounds__(256)
void prop128_bf16out(const unsigned int* __restrict__ Hsrc,
                     const int* __restrict__ start, const int* __restrict__ cnt,
                     const int* __restrict__ src_s, const float* __restrict__ norm_s,
                     const float* __restrict__ dis,
                     const float* __restrict__ bvec,
                     const float* __restrict__ g, const float* __restrict__ be,
                     const float* __restrict__ mean, const float* __restrict__ var,
                     unsigned int* __restrict__ Outb, int N) {
  int w = (int)((blockIdx.x * blockDim.x + threadIdx.x) >> 6);
  int lane = threadIdx.x & 63;
  if (w >= N) return;
  PROP_GATHER_BODY
  float x0 = acc0 + bvec[c0];
  float x1 = acc1 + bvec[c0 + 1];
  float s0 = g[c0] * rsqrtf(var[c0] + BN_EPS);
  float s1 = g[c0 + 1] * rsqrtf(var[c0 + 1] + BN_EPS);
  x0 = fmaxf((x0 - mean[c0]) * s0 + be[c0], 0.f);
  x1 = fmaxf((x1 - mean[c0 + 1]) * s1 + be[c0 + 1], 0.f);
  unsigned int packed = (unsigned int)f2bf(x0) | ((unsigned int)f2bf(x1) << 16);
  Outb[(size_t)w * 64 + lane] = packed;
}

// prop2: h2 = relu(bn2(agg + b2 + res)); fused h3[w] = dot(h2_row, W3)
static __global__ __launch_bounds__(256)
void prop128_w3out(const unsigned int* __restrict__ Hsrc,
                   const int* __restrict__ start, const int* __restrict__ cnt,
                   const int* __restrict__ src_s, const float* __restrict__ norm_s,
                   const float* __restrict__ dis,
                   const float* __restrict__ bvec,
                   const float* __restrict__ g, const float* __restrict__ be,
                   const float* __restrict__ mean, const float* __restrict__ var,
                   const float* __restrict__ res, const float* __restrict__ W3,
                   float* __restrict__ h3, int N) {
  int w = (int)((blockIdx.x * blockDim.x + threadIdx.x) >> 6);
  int lane = threadIdx.x & 63;
  if (w >= N) return;
  PROP_GATHER_BODY
  float x0 = acc0 + bvec[c0] + res[(size_t)w * 128 + c0];
  float x1 = acc1 + bvec[c0 + 1] + res[(size_t)w * 128 + c0 + 1];
  float s0 = g[c0] * rsqrtf(var[c0] + BN_EPS);
  float s1 = g[c0 + 1] * rsqrtf(var[c0 + 1] + BN_EPS);
  x0 = fmaxf((x0 - mean[c0]) * s0 + be[c0], 0.f);
  x1 = fmaxf((x1 - mean[c0 + 1]) * s1 + be[c0 + 1], 0.f);
  float v = x0 * W3[c0] + x1 * W3[c0 + 1];
#pragma unroll
  for (int off = 32; off > 0; off >>= 1) v += __shfl_down(v, off, 64);
  if (lane == 0) h3[w] = v;
}

// ---------------------------------------------------------------- final 1-wide propagation

static __global__ void prop3_kernel(const float* __restrict__ h3,
                                    const int* __restrict__ start, const int* __restrict__ cnt,
                                    const int* __restrict__ src_s, const float* __restrict__ norm_s,
                                    const float* __restrict__ dis, const float* __restrict__ b3,
                                    float* __restrict__ out, int N) {
  int i = blockIdx.x * blockDim.x + threadIdx.x;
  if (i >= N) return;
  float d = dis[i];
  float acc = d * d * h3[i];
  int s = start[i], n = cnt[i];
  for (int k = 0; k < n; ++k)
    acc = fmaf(norm_s[s + k], h3[src_s[s + k]], acc);
  out[i] = acc + b3[0];
}

// ---------------------------------------------------------------- launch

extern "C" void kernel_launch(void* const* d_in, const int* in_sizes, int n_in,
                              void* d_out, int out_size, void* d_ws, size_t ws_size,
                              hipStream_t stream) {
  const float* x    = (const float*)d_in[0];
  const int*   ei   = (const int*)d_in[1];
  const float* ew   = (const float*)d_in[2];
  const float* W1   = (const float*)d_in[3];
  const float* b1   = (const float*)d_in[4];
  const float* W2   = (const float*)d_in[5];
  const float* b2   = (const float*)d_in[6];
  const float* W3   = (const float*)d_in[7];
  const float* b3   = (const float*)d_in[8];
  const float* Wres = (const float*)d_in[9];
  const float* g1   = (const float*)d_in[10];
  const float* be1  = (const float*)d_in[11];
  const float* m1   = (const float*)d_in[12];
  const float* v1   = (const float*)d_in[13];
  const float* g2   = (const float*)d_in[14];
  const float* be2  = (const float*)d_in[15];
  const float* m2   = (const float*)d_in[16];
  const float* v2   = (const float*)d_in[17];

  int Hh = in_sizes[4];            // 128
  int V  = in_sizes[3] / Hh;       // 256
  int N  = in_sizes[0] / V;        // 100000
  int E  = in_sizes[2];            // 1600000
  const int* row = ei;
  const int* col = ei + E;

  int Mp = ((N + 127) / 128) * 128;  // pad for 128-row gemm2 tiles

  char* p = (char*)d_ws;
  auto alloc = [&](size_t bytes) -> char* {
    char* r = p;
    p += (bytes + 255) & ~(size_t)255;
    return r;
  };
  float* deg    = (float*)alloc((size_t)N * 4);   // becomes dis in place
  int*   cnt    = (int*)  alloc((size_t)N * 4);
  int*   startA = (int*)  alloc((size_t)N * 4);
  int*   cursor = (int*)  alloc((size_t)N * 4);
  int*   blkSum = (int*)  alloc(256 * 4);
  int*   blkOff = (int*)  alloc(256 * 4);
  int*   src_s  = (int*)  alloc((size_t)E * 4);
  float* norm_s = (float*)alloc((size_t)E * 4);
  float* h3     = (float*)alloc((size_t)N * 4);
  unsigned short* BT1 = (unsigned short*)alloc((size_t)256 * 256 * 2);
  unsigned short* BT2 = (unsigned short*)alloc((size_t)128 * 128 * 2);
  unsigned short* bufG  = (unsigned short*)alloc((size_t)Mp * 128 * 2);  // h0, then xW2 (bf16)
  unsigned short* bufH1 = (unsigned short*)alloc((size_t)Mp * 128 * 2);  // h1 bf16
  float* bufRes = (float*)alloc((size_t)Mp * 128 * 4);                   // x@Wres fp32
  (void)ws_size; (void)n_in; (void)out_size;

  int TB = 256;
  init_deg_cnt<<<(N + TB - 1) / TB, TB, 0, stream>>>(deg, cnt, N);
  hist_kernel<<<(E + TB - 1) / TB, TB, 0, stream>>>(col, ew, deg, cnt, E);
  dis_kernel<<<(N + TB - 1) / TB, TB, 0, stream>>>(deg, N);

  int nb = (N + SCAN_B * SCAN_I - 1) / (SCAN_B * SCAN_I);
  scanA<<<nb, SCAN_B, 0, stream>>>(cnt, startA, blkSum, N);
  scanB<<<1, 256, 0, stream>>>(blkSum, blkOff, nb);
  scanC<<<(N + TB - 1) / TB, TB, 0, stream>>>(startA, cursor, blkOff, N);
  scatter_kernel<<<(E + TB - 1) / TB, TB, 0, stream>>>(row, col, ew, deg, cursor,
                                                       src_s, norm_s, E);

  cast_weights<<<(256 * 256 + 128 * 128 + TB - 1) / TB, TB, 0, stream>>>(W1, Wres, W2, BT1, BT2);

  // GEMM1: x @ [W1|Wres] -> bufG (bf16), bufRes (fp32)
  gemm1_mfma<<<Mp / 64, 256, 0, stream>>>(x, BT1, bufG, bufRes, N);

  // prop1: h1 = relu(bn1(agg(h0) + b1)) -> bufH1 (bf16)
  int propBlocks = (int)(((size_t)N * 64 + TB - 1) / TB);
  prop128_bf16out<<<propBlocks, TB, 0, stream>>>((const unsigned int*)bufG, startA, cnt,
                                                 src_s, norm_s, deg, b1, g1, be1, m1, v1,
                                                 (unsigned int*)bufH1, N);

  // GEMM2: h1 @ W2 -> bufG (bf16, reused)
  gemm2_mfma<<<Mp / 128, 256, 0, stream>>>(bufH1, BT2, bufG, Mp);

  // prop2 + fused W3: h3 = relu(bn2(agg(xW2) + b2 + res)) . W3
  prop128_w3out<<<propBlocks, TB, 0, stream>>>((const unsigned int*)bufG, startA, cnt,
                                               src_s, norm_s, deg, b2, g2, be2, m2, v2,
                                               bufRes, W3, h3, N);

  // out = agg(h3) + b3
  prop3_kernel<<<(N + TB - 1) / TB, TB, 0, stream>>>(h3, startA, cnt, src_s, norm_s,
                                                     deg, b3, (float*)d_out, N);
}

// Round 5
// 553.399 us; speedup vs baseline: 1.8640x; 1.1857x over previous
//
#include <hip/hip_runtime.h>
#include <hip/hip_bf16.h>

#define BN_EPS 1e-5f

using short8 = __attribute__((ext_vector_type(8))) short;
using f32x4  = __attribute__((ext_vector_type(4))) float;

#define FIX_SCALE 1048576.0f          // 2^20
#define FIX_MASK  ((1ULL << 42) - 1)
#define CNT_ONE   (1ULL << 42)

static __device__ __forceinline__ unsigned short f2bf(float f) {
  unsigned int u = __float_as_uint(f);
  unsigned int r = (u + 0x7fffu + ((u >> 16) & 1u)) >> 16;
  return (unsigned short)r;
}

// ---------------------------------------------------------------- graph prep

// one packed 64-bit atomic per edge: cnt in [63:42], fixed-point ew-sum in [41:0]
static __global__ void hist_kernel(const int* __restrict__ col,
                                   const float* __restrict__ ew,
                                   unsigned long long* __restrict__ packed, int E) {
  int e = blockIdx.x * blockDim.x + threadIdx.x;
  if (e < E) {
    int c = col[e];
    unsigned long long fx = (unsigned long long)(unsigned int)(ew[e] * FIX_SCALE + 0.5f);
    atomicAdd(&packed[c], CNT_ONE | fx);
  }
}

// unpack: dis = rsqrt(1 + fixsum*2^-20), cnt
static __global__ void unpack_kernel(const unsigned long long* __restrict__ packed,
                                     float* __restrict__ dis, int* __restrict__ cnt, int N) {
  int i = blockIdx.x * blockDim.x + threadIdx.x;
  if (i < N) {
    unsigned long long v = packed[i];
    cnt[i] = (int)(v >> 42);
    float deg = 1.0f + (float)(v & FIX_MASK) * (1.0f / FIX_SCALE);
    dis[i] = rsqrtf(deg);   // deg >= 1 always (self-loop)
  }
}

#define SCAN_B 256
#define SCAN_I 4
static __global__ void scanA(const int* __restrict__ cnt, int* __restrict__ start,
                             int* __restrict__ blkSum, int N) {
  __shared__ int sh[SCAN_B];
  int t = threadIdx.x;
  int base = blockIdx.x * SCAN_B * SCAN_I + t * SCAN_I;
  int v[SCAN_I];
  int tot = 0;
#pragma unroll
  for (int j = 0; j < SCAN_I; ++j) {
    v[j] = (base + j < N) ? cnt[base + j] : 0;
    tot += v[j];
  }
  sh[t] = tot;
  __syncthreads();
  int self = tot;
  for (int off = 1; off < SCAN_B; off <<= 1) {
    int add = (t >= off) ? sh[t - off] : 0;
    __syncthreads();
    sh[t] += add;
    __syncthreads();
  }
  int excl = sh[t] - self;
  if (t == SCAN_B - 1) blkSum[blockIdx.x] = sh[t];
  int run = excl;
#pragma unroll
  for (int j = 0; j < SCAN_I; ++j) {
    if (base + j < N) start[base + j] = run;
    run += v[j];
  }
}

static __global__ void scanB(const int* __restrict__ blkSum, int* __restrict__ blkOff, int nb) {
  __shared__ int sh[256];
  int t = threadIdx.x;
  int v = (t < nb) ? blkSum[t] : 0;
  sh[t] = v;
  __syncthreads();
  for (int off = 1; off < 256; off <<= 1) {
    int add = (t >= off) ? sh[t - off] : 0;
    __syncthreads();
    sh[t] += add;
    __syncthreads();
  }
  if (t < nb) blkOff[t] = sh[t] - v;
}

static __global__ void scanC(int* start, int* cursor, const int* __restrict__ blkOff, int N) {
  int i = blockIdx.x * blockDim.x + threadIdx.x;
  if (i < N) {
    int s = start[i] + blkOff[i / (SCAN_B * SCAN_I)];
    start[i] = s;
    cursor[i] = s;
  }
}

// one atomic + one packed 8B store per edge: edges[pos] = (src, bits(norm))
static __global__ void scatter_kernel(const int* __restrict__ row, const int* __restrict__ col,
                                      const float* __restrict__ ew, const float* __restrict__ dis,
                                      int* cursor, int2* __restrict__ edges, int E) {
  int e = blockIdx.x * blockDim.x + threadIdx.x;
  if (e < E) {
    int r = row[e], c = col[e];
    int pos = atomicAdd(&cursor[c], 1);
    float nrm = dis[r] * ew[e] * dis[c];
    edges[pos] = make_int2(r, __float_as_int(nrm));
  }
}

// ------------------------------------------------- weight cast (bf16, n-major)

static __global__ void cast_weights(const float* __restrict__ W1, const float* __restrict__ Wres,
                                    const float* __restrict__ W2,
                                    unsigned short* __restrict__ BT1,
                                    unsigned short* __restrict__ BT2) {
  int i = blockIdx.x * blockDim.x + threadIdx.x;
  if (i < 256 * 256) {
    int n = i >> 8, k = i & 255;
    float v = (n < 128) ? W1[k * 128 + n] : Wres[k * 128 + (n - 128)];
    BT1[i] = f2bf(v);
  } else if (i < 256 * 256 + 128 * 128) {
    int j = i - 256 * 256;
    int n = j >> 7, k = j & 127;
    BT2[j] = f2bf(W2[k * 128 + n]);
  }
}

// ---------------------------------------------------------------- GEMM1 (MFMA)
// C[M x 256] = A[M x 256] (fp32 -> bf16 staged) @ BT[256 x 256] (n-major).
// 256 thr / 4 waves, tile 64(M) x 256(N); wave owns 64-wide n-slice.
// Cols <128 -> C0 bf16; cols >=128 -> C1 fp32. LDS rows padded to 40 shorts.

static __global__ __launch_bounds__(256)
void gemm1_mfma(const float* __restrict__ A, const unsigned short* __restrict__ BT,
                unsigned short* __restrict__ C0, float* __restrict__ C1, int M) {
  __shared__ unsigned short As[64 * 40];
  __shared__ unsigned short Bs[256 * 40];
  int t = threadIdx.x;
  int wv = t >> 6, lane = t & 63;
  int quad = lane >> 4, l15 = lane & 15;
  int m0 = blockIdx.x * 64;

  f32x4 acc[4][4];
#pragma unroll
  for (int i = 0; i < 4; ++i)
#pragma unroll
    for (int j = 0; j < 4; ++j) acc[i][j] = (f32x4){0.f, 0.f, 0.f, 0.f};

  int ar = t >> 2;
  int ac = (t & 3) * 8;
  bool avalid = (m0 + ar) < M;
  const float* Arow = A + (size_t)(m0 + ar) * 256 + ac;
  const unsigned short* Brow = BT + (size_t)t * 256;

  for (int k0 = 0; k0 < 256; k0 += 32) {
    float4 a0 = make_float4(0.f, 0.f, 0.f, 0.f), a1 = a0;
    if (avalid) {
      a0 = *(const float4*)(Arow + k0);
      a1 = *(const float4*)(Arow + k0 + 4);
    }
    short8 av;
    av[0] = (short)f2bf(a0.x); av[1] = (short)f2bf(a0.y);
    av[2] = (short)f2bf(a0.z); av[3] = (short)f2bf(a0.w);
    av[4] = (short)f2bf(a1.x); av[5] = (short)f2bf(a1.y);
    av[6] = (short)f2bf(a1.z); av[7] = (short)f2bf(a1.w);
    *(short8*)&As[ar * 40 + ac] = av;

    short8 b0 = *(const short8*)(Brow + k0);
    short8 b1 = *(const short8*)(Brow + k0 + 8);
    short8 b2 = *(const short8*)(Brow + k0 + 16);
    short8 b3 = *(const short8*)(Brow + k0 + 24);
    *(short8*)&Bs[t * 40 + 0]  = b0;
    *(short8*)&Bs[t * 40 + 8]  = b1;
    *(short8*)&Bs[t * 40 + 16] = b2;
    *(short8*)&Bs[t * 40 + 24] = b3;
    __syncthreads();

    short8 af[4], bf[4];
#pragma unroll
    for (int mt = 0; mt < 4; ++mt)
      af[mt] = *(const short8*)&As[(mt * 16 + l15) * 40 + quad * 8];
#pragma unroll
    for (int nt = 0; nt < 4; ++nt)
      bf[nt] = *(const short8*)&Bs[(wv * 64 + nt * 16 + l15) * 40 + quad * 8];
#pragma unroll
    for (int mt = 0; mt < 4; ++mt)
#pragma unroll
      for (int nt = 0; nt < 4; ++nt)
        acc[mt][nt] = __builtin_amdgcn_mfma_f32_16x16x32_bf16(af[mt], bf[nt], acc[mt][nt], 0, 0, 0);
    __syncthreads();
  }

  int nbase = wv * 64;
#pragma unroll
  for (int mt = 0; mt < 4; ++mt) {
#pragma unroll
    for (int nt = 0; nt < 4; ++nt) {
      int n = nbase + nt * 16 + l15;
#pragma unroll
      for (int reg = 0; reg < 4; ++reg) {
        size_t m = (size_t)(m0 + mt * 16 + quad * 4 + reg);
        if (nbase < 128) C0[m * 128 + n] = f2bf(acc[mt][nt][reg]);
        else             C1[m * 128 + (n - 128)] = acc[mt][nt][reg];
      }
    }
  }
}

// ---------------------------------------------------------------- GEMM2 (MFMA)

static __global__ __launch_bounds__(256)
void gemm2_mfma(const unsigned short* __restrict__ A, const unsigned short* __restrict__ BT,
                unsigned short* __restrict__ C, int Mp) {
  __shared__ unsigned short As[128 * 40];
  __shared__ unsigned short Bs[128 * 40];
  int t = threadIdx.x;
  int wv = t >> 6, lane = t & 63;
  int quad = lane >> 4, l15 = lane & 15;
  int m0 = blockIdx.x * 128;

  f32x4 acc[4][4];
#pragma unroll
  for (int i = 0; i < 4; ++i)
#pragma unroll
    for (int j = 0; j < 4; ++j) acc[i][j] = (f32x4){0.f, 0.f, 0.f, 0.f};

  int sr = t >> 1, sc = (t & 1) * 16;

  for (int k0 = 0; k0 < 128; k0 += 32) {
    short8 a0 = *(const short8*)(A + (size_t)(m0 + sr) * 128 + k0 + sc);
    short8 a1 = *(const short8*)(A + (size_t)(m0 + sr) * 128 + k0 + sc + 8);
    *(short8*)&As[sr * 40 + sc]     = a0;
    *(short8*)&As[sr * 40 + sc + 8] = a1;
    short8 b0 = *(const short8*)(BT + (size_t)sr * 128 + k0 + sc);
    short8 b1 = *(const short8*)(BT + (size_t)sr * 128 + k0 + sc + 8);
    *(short8*)&Bs[sr * 40 + sc]     = b0;
    *(short8*)&Bs[sr * 40 + sc + 8] = b1;
    __syncthreads();

    int mb = (wv >> 1) * 64, nb = (wv & 1) * 64;
    short8 af[4], bf[4];
#pragma unroll
    for (int mt = 0; mt < 4; ++mt)
      af[mt] = *(const short8*)&As[(mb + mt * 16 + l15) * 40 + quad * 8];
#pragma unroll
    for (int nt = 0; nt < 4; ++nt)
      bf[nt] = *(const short8*)&Bs[(nb + nt * 16 + l15) * 40 + quad * 8];
#pragma unroll
    for (int mt = 0; mt < 4; ++mt)
#pragma unroll
      for (int nt = 0; nt < 4; ++nt)
        acc[mt][nt] = __builtin_amdgcn_mfma_f32_16x16x32_bf16(af[mt], bf[nt], acc[mt][nt], 0, 0, 0);
    __syncthreads();
  }

  int mb = (wv >> 1) * 64, nb = (wv & 1) * 64;
#pragma unroll
  for (int mt = 0; mt < 4; ++mt)
#pragma unroll
    for (int nt = 0; nt < 4; ++nt) {
      int n = nb + nt * 16 + l15;
#pragma unroll
      for (int reg = 0; reg < 4; ++reg) {
        size_t m = (size_t)(m0 + mb + mt * 16 + quad * 4 + reg);
        C[m * 128 + n] = f2bf(acc[mt][nt][reg]);
      }
    }
  (void)Mp;
}

// ---------------------------------------------------------------- propagation core
// One wave per destination node; lane holds 2 channels (one bf16x2 word).
// Edge (src, norm) packed int2; lane-parallel load + shfl broadcast; gathers
// in unrolled groups of 8 independent loads.

#define PROP_GATHER_BODY                                                        \
  int c0 = lane * 2;                                                            \
  float d = dis[w];                                                             \
  float d2 = d * d;                                                             \
  float acc0, acc1;                                                             \
  {                                                                             \
    unsigned int u = Hsrc[(size_t)w * 64 + lane];                               \
    acc0 = d2 * __uint_as_float(u << 16);                                       \
    acc1 = d2 * __uint_as_float(u & 0xffff0000u);                               \
  }                                                                             \
  int s = start[w], n = cnt[w];                                                 \
  int k = 0;                                                                    \
  while (k < n) {                                                               \
    int chunk = min(n - k, 64);                                                 \
    int idx = 0;                                                                \
    float wt = 0.f;                                                             \
    if (lane < chunk) {                                                         \
      int2 ev = edges[s + k + lane];                                            \
      idx = ev.x;                                                               \
      wt  = __int_as_float(ev.y);                                               \
    }                                                                           \
    for (int j = 0; j < chunk; j += 8) {                                        \
      int   i0 = __shfl(idx, j + 0, 64), i1 = __shfl(idx, j + 1, 64);           \
      int   i2 = __shfl(idx, j + 2, 64), i3 = __shfl(idx, j + 3, 64);           \
      int   i4 = __shfl(idx, j + 4, 64), i5 = __shfl(idx, j + 5, 64);           \
      int   i6 = __shfl(idx, j + 6, 64), i7 = __shfl(idx, j + 7, 64);           \
      float w0 = __shfl(wt, j + 0, 64), w1 = __shfl(wt, j + 1, 64);             \
      float w2 = __shfl(wt, j + 2, 64), w3 = __shfl(wt, j + 3, 64);             \
      float w4 = __shfl(wt, j + 4, 64), w5 = __shfl(wt, j + 5, 64);             \
      float w6 = __shfl(wt, j + 6, 64), w7 = __shfl(wt, j + 7, 64);             \
      unsigned int u0 = Hsrc[(size_t)i0 * 64 + lane];                           \
      unsigned int u1 = Hsrc[(size_t)i1 * 64 + lane];                           \
      unsigned int u2 = Hsrc[(size_t)i2 * 64 + lane];                           \
      unsigned int u3 = Hsrc[(size_t)i3 * 64 + lane];                           \
      unsigned int u4 = Hsrc[(size_t)i4 * 64 + lane];                           \
      unsigned int u5 = Hsrc[(size_t)i5 * 64 + lane];                           \
      unsigned int u6 = Hsrc[(size_t)i6 * 64 + lane];                           \
      unsigned int u7 = Hsrc[(size_t)i7 * 64 + lane];                           \
      acc0 = fmaf(w0, __uint_as_float(u0 << 16), acc0);                         \
      acc1 = fmaf(w0, __uint_as_float(u0 & 0xffff0000u), acc1);                 \
      acc0 = fmaf(w1, __uint_as_float(u1 << 16), acc0);                         \
      acc1 = fmaf(w1, __uint_as_float(u1 & 0xffff0000u), acc1);                 \
      acc0 = fmaf(w2, __uint_as_float(u2 << 16), acc0);                         \
      acc1 = fmaf(w2, __uint_as_float(u2 & 0xffff0000u), acc1);                 \
      acc0 = fmaf(w3, __uint_as_float(u3 << 16), acc0);                         \
      acc1 = fmaf(w3, __uint_as_float(u3 & 0xffff0000u), acc1);                 \
      acc0 = fmaf(w4, __uint_as_float(u4 << 16), acc0);                         \
      acc1 = fmaf(w4, __uint_as_float(u4 & 0xffff0000u), acc1);                 \
      acc0 = fmaf(w5, __uint_as_float(u5 << 16), acc0);                         \
      acc1 = fmaf(w5, __uint_as_float(u5 & 0xffff0000u), acc1);                 \
      acc0 = fmaf(w6, __uint_as_float(u6 << 16), acc0);                         \
      acc1 = fmaf(w6, __uint_as_float(u6 & 0xffff0000u), acc1);                 \
      acc0 = fmaf(w7, __uint_as_float(u7 << 16), acc0);                         \
      acc1 = fmaf(w7, __uint_as_float(u7 & 0xffff0000u), acc1);                 \
    }                                                                           \
    k += chunk;                                                                 \
  }

// prop1: h1 = relu(bn1(agg + b1)) -> bf16 packed output
static __global__ __launch_bounds__(256)
void prop128_bf16out(const unsigned int* __restrict__ Hsrc,
                     const int* __restrict__ start, const int* __restrict__ cnt,
                     const int2* __restrict__ edges,
                     const float* __restrict__ dis,
                     const float* __restrict__ bvec,
                     const float* __restrict__ g, const float* __restrict__ be,
                     const float* __restrict__ mean, const float* __restrict__ var,
                     unsigned int* __restrict__ Outb, int N) {
  int w = (int)((blockIdx.x * blockDim.x + threadIdx.x) >> 6);
  int lane = threadIdx.x & 63;
  if (w >= N) return;
  PROP_GATHER_BODY
  float x0 = acc0 + bvec[c0];
  float x1 = acc1 + bvec[c0 + 1];
  float s0 = g[c0] * rsqrtf(var[c0] + BN_EPS);
  float s1 = g[c0 + 1] * rsqrtf(var[c0 + 1] + BN_EPS);
  x0 = fmaxf((x0 - mean[c0]) * s0 + be[c0], 0.f);
  x1 = fmaxf((x1 - mean[c0 + 1]) * s1 + be[c0 + 1], 0.f);
  unsigned int packed = (unsigned int)f2bf(x0) | ((unsigned int)f2bf(x1) << 16);
  Outb[(size_t)w * 64 + lane] = packed;
}

// prop2: h2 = relu(bn2(agg + b2 + res)); fused h3[w] = dot(h2_row, W3)
static __global__ __launch_bounds__(256)
void prop128_w3out(const unsigned int* __restrict__ Hsrc,
                   const int* __restrict__ start, const int* __restrict__ cnt,
                   const int2* __restrict__ edges,
                   const float* __restrict__ dis,
                   const float* __restrict__ bvec,
                   const float* __restrict__ g, const float* __restrict__ be,
                   const float* __restrict__ mean, const float* __restrict__ var,
                   const float* __restrict__ res, const float* __restrict__ W3,
                   float* __restrict__ h3, int N) {
  int w = (int)((blockIdx.x * blockDim.x + threadIdx.x) >> 6);
  int lane = threadIdx.x & 63;
  if (w >= N) return;
  PROP_GATHER_BODY
  float x0 = acc0 + bvec[c0] + res[(size_t)w * 128 + c0];
  float x1 = acc1 + bvec[c0 + 1] + res[(size_t)w * 128 + c0 + 1];
  float s0 = g[c0] * rsqrtf(var[c0] + BN_EPS);
  float s1 = g[c0 + 1] * rsqrtf(var[c0 + 1] + BN_EPS);
  x0 = fmaxf((x0 - mean[c0]) * s0 + be[c0], 0.f);
  x1 = fmaxf((x1 - mean[c0 + 1]) * s1 + be[c0 + 1], 0.f);
  float v = x0 * W3[c0] + x1 * W3[c0 + 1];
#pragma unroll
  for (int off = 32; off > 0; off >>= 1) v += __shfl_down(v, off, 64);
  if (lane == 0) h3[w] = v;
}

// ---------------------------------------------------------------- final 1-wide propagation

static __global__ void prop3_kernel(const float* __restrict__ h3,
                                    const int* __restrict__ start, const int* __restrict__ cnt,
                                    const int2* __restrict__ edges,
                                    const float* __restrict__ dis, const float* __restrict__ b3,
                                    float* __restrict__ out, int N) {
  int i = blockIdx.x * blockDim.x + threadIdx.x;
  if (i >= N) return;
  float d = dis[i];
  float acc = d * d * h3[i];
  int s = start[i], n = cnt[i];
  for (int k = 0; k < n; ++k) {
    int2 ev = edges[s + k];
    acc = fmaf(__int_as_float(ev.y), h3[ev.x], acc);
  }
  out[i] = acc + b3[0];
}

// ---------------------------------------------------------------- launch

extern "C" void kernel_launch(void* const* d_in, const int* in_sizes, int n_in,
                              void* d_out, int out_size, void* d_ws, size_t ws_size,
                              hipStream_t stream) {
  const float* x    = (const float*)d_in[0];
  const int*   ei   = (const int*)d_in[1];
  const float* ew   = (const float*)d_in[2];
  const float* W1   = (const float*)d_in[3];
  const float* b1   = (const float*)d_in[4];
  const float* W2   = (const float*)d_in[5];
  const float* b2   = (const float*)d_in[6];
  const float* W3   = (const float*)d_in[7];
  const float* b3   = (const float*)d_in[8];
  const float* Wres = (const float*)d_in[9];
  const float* g1   = (const float*)d_in[10];
  const float* be1  = (const float*)d_in[11];
  const float* m1   = (const float*)d_in[12];
  const float* v1   = (const float*)d_in[13];
  const float* g2   = (const float*)d_in[14];
  const float* be2  = (const float*)d_in[15];
  const float* m2   = (const float*)d_in[16];
  const float* v2   = (const float*)d_in[17];

  int Hh = in_sizes[4];            // 128
  int V  = in_sizes[3] / Hh;       // 256
  int N  = in_sizes[0] / V;        // 100000
  int E  = in_sizes[2];            // 1600000
  const int* row = ei;
  const int* col = ei + E;

  int Mp = ((N + 127) / 128) * 128;

  char* p = (char*)d_ws;
  auto alloc = [&](size_t bytes) -> char* {
    char* r = p;
    p += (bytes + 255) & ~(size_t)255;
    return r;
  };
  unsigned long long* packed = (unsigned long long*)alloc((size_t)N * 8);
  float* dis    = (float*)alloc((size_t)N * 4);
  int*   cnt    = (int*)  alloc((size_t)N * 4);
  int*   startA = (int*)  alloc((size_t)N * 4);
  int*   cursor = (int*)  alloc((size_t)N * 4);
  int*   blkSum = (int*)  alloc(256 * 4);
  int*   blkOff = (int*)  alloc(256 * 4);
  int2*  edges  = (int2*) alloc((size_t)E * 8);
  float* h3     = (float*)alloc((size_t)N * 4);
  unsigned short* BT1 = (unsigned short*)alloc((size_t)256 * 256 * 2);
  unsigned short* BT2 = (unsigned short*)alloc((size_t)128 * 128 * 2);
  unsigned short* bufG  = (unsigned short*)alloc((size_t)Mp * 128 * 2);  // h0, then h1W2 (bf16)
  unsigned short* bufH1 = (unsigned short*)alloc((size_t)Mp * 128 * 2);  // h1 bf16
  float* bufRes = (float*)alloc((size_t)Mp * 128 * 4);                   // x@Wres fp32
  (void)ws_size; (void)n_in; (void)out_size;

  int TB = 256;
  hipMemsetAsync(packed, 0, (size_t)N * 8, stream);
  hist_kernel<<<(E + TB - 1) / TB, TB, 0, stream>>>(col, ew, packed, E);
  unpack_kernel<<<(N + TB - 1) / TB, TB, 0, stream>>>(packed, dis, cnt, N);

  int nb = (N + SCAN_B * SCAN_I - 1) / (SCAN_B * SCAN_I);
  scanA<<<nb, SCAN_B, 0, stream>>>(cnt, startA, blkSum, N);
  scanB<<<1, 256, 0, stream>>>(blkSum, blkOff, nb);
  scanC<<<(N + TB - 1) / TB, TB, 0, stream>>>(startA, cursor, blkOff, N);
  scatter_kernel<<<(E + TB - 1) / TB, TB, 0, stream>>>(row, col, ew, dis, cursor, edges, E);

  cast_weights<<<(256 * 256 + 128 * 128 + TB - 1) / TB, TB, 0, stream>>>(W1, Wres, W2, BT1, BT2);

  // GEMM1: x @ [W1|Wres] -> bufG (bf16), bufRes (fp32)
  gemm1_mfma<<<Mp / 64, 256, 0, stream>>>(x, BT1, bufG, bufRes, N);

  // prop1: h1 = relu(bn1(agg(h0) + b1)) -> bufH1 (bf16)
  int propBlocks = (int)(((size_t)N * 64 + TB - 1) / TB);
  prop128_bf16out<<<propBlocks, TB, 0, stream>>>((const unsigned int*)bufG, startA, cnt,
                                                 edges, dis, b1, g1, be1, m1, v1,
                                                 (unsigned int*)bufH1, N);

  // GEMM2: h1 @ W2 -> bufG (bf16, reused)
  gemm2_mfma<<<Mp / 128, 256, 0, stream>>>(bufH1, BT2, bufG, Mp);

  // prop2 + fused W3: h3 = relu(bn2(agg(h1W2) + b2 + res)) . W3
  prop128_w3out<<<propBlocks, TB, 0, stream>>>((const unsigned int*)bufG, startA, cnt,
                                               edges, dis, b2, g2, be2, m2, v2,
                                               bufRes, W3, h3, N);

  // out = agg(h3) + b3
  prop3_kernel<<<(N + TB - 1) / TB, TB, 0, stream>>>(h3, startA, cnt, edges,
                                                     dis, b3, (float*)d_out, N);
}

// Round 6
// 527.087 us; speedup vs baseline: 1.9570x; 1.0499x over previous
//
#include <hip/hip_runtime.h>
#include <hip/hip_bf16.h>

#define BN_EPS 1e-5f

using short8 = __attribute__((ext_vector_type(8))) short;
using f32x4  = __attribute__((ext_vector_type(4))) float;

#define FIX_SCALE 1048576.0f          // 2^20
#define FIX_MASK  ((1ULL << 42) - 1)
#define CNT_ONE   (1ULL << 42)

static __device__ __forceinline__ unsigned short f2bf(float f) {
  unsigned int u = __float_as_uint(f);
  unsigned int r = (u + 0x7fffu + ((u >> 16) & 1u)) >> 16;
  return (unsigned short)r;
}

// ---------------------------------------------------------------- graph prep

// one packed 64-bit atomic per edge: cnt in [63:42], fixed-point ew-sum in [41:0].
// atomicAdd's return value gives this edge's insertion rank among same-col edges.
static __global__ void hist_kernel(const int* __restrict__ col,
                                   const float* __restrict__ ew,
                                   unsigned long long* __restrict__ packed,
                                   unsigned short* __restrict__ rank, int E) {
  int e = blockIdx.x * blockDim.x + threadIdx.x;
  if (e < E) {
    int c = col[e];
    unsigned long long fx = (unsigned long long)(unsigned int)(ew[e] * FIX_SCALE + 0.5f);
    unsigned long long old = atomicAdd(&packed[c], CNT_ONE | fx);
    rank[e] = (unsigned short)(old >> 42);
  }
}

// unpack: dis = rsqrt(1 + fixsum*2^-20), cnt
static __global__ void unpack_kernel(const unsigned long long* __restrict__ packed,
                                     float* __restrict__ dis, int* __restrict__ cnt, int N) {
  int i = blockIdx.x * blockDim.x + threadIdx.x;
  if (i < N) {
    unsigned long long v = packed[i];
    cnt[i] = (int)(v >> 42);
    float deg = 1.0f + (float)(v & FIX_MASK) * (1.0f / FIX_SCALE);
    dis[i] = rsqrtf(deg);   // deg >= 1 always (self-loop)
  }
}

#define SCAN_B 256
#define SCAN_I 4
static __global__ void scanA(const int* __restrict__ cnt, int* __restrict__ start,
                             int* __restrict__ blkSum, int N) {
  __shared__ int sh[SCAN_B];
  int t = threadIdx.x;
  int base = blockIdx.x * SCAN_B * SCAN_I + t * SCAN_I;
  int v[SCAN_I];
  int tot = 0;
#pragma unroll
  for (int j = 0; j < SCAN_I; ++j) {
    v[j] = (base + j < N) ? cnt[base + j] : 0;
    tot += v[j];
  }
  sh[t] = tot;
  __syncthreads();
  int self = tot;
  for (int off = 1; off < SCAN_B; off <<= 1) {
    int add = (t >= off) ? sh[t - off] : 0;
    __syncthreads();
    sh[t] += add;
    __syncthreads();
  }
  int excl = sh[t] - self;
  if (t == SCAN_B - 1) blkSum[blockIdx.x] = sh[t];
  int run = excl;
#pragma unroll
  for (int j = 0; j < SCAN_I; ++j) {
    if (base + j < N) start[base + j] = run;
    run += v[j];
  }
}

static __global__ void scanB(const int* __restrict__ blkSum, int* __restrict__ blkOff, int nb) {
  __shared__ int sh[256];
  int t = threadIdx.x;
  int v = (t < nb) ? blkSum[t] : 0;
  sh[t] = v;
  __syncthreads();
  for (int off = 1; off < 256; off <<= 1) {
    int add = (t >= off) ? sh[t - off] : 0;
    __syncthreads();
    sh[t] += add;
    __syncthreads();
  }
  if (t < nb) blkOff[t] = sh[t] - v;
}

static __global__ void scanC(int* start, const int* __restrict__ blkOff, int N) {
  int i = blockIdx.x * blockDim.x + threadIdx.x;
  if (i < N) start[i] += blkOff[i / (SCAN_B * SCAN_I)];
}

// atomic-free placement: pos = start[col] + rank. edges[pos] = (src, dis[src]*ew)
// (the destination's dis factor is folded into the prop epilogue).
static __global__ void place_kernel(const int* __restrict__ row, const int* __restrict__ col,
                                    const float* __restrict__ ew, const float* __restrict__ dis,
                                    const int* __restrict__ start,
                                    const unsigned short* __restrict__ rank,
                                    long long* __restrict__ edges, int E) {
  int e = blockIdx.x * blockDim.x + threadIdx.x;
  if (e < E) {
    int r = row[e], c = col[e];
    int pos = start[c] + (int)rank[e];
    float nrm = dis[r] * ew[e];
    long long v = ((long long)__float_as_int(nrm) << 32) | (unsigned int)r;
    __builtin_nontemporal_store(v, &edges[pos]);
  }
}

// ------------------------------------------------- weight cast (bf16, n-major)

static __global__ void cast_weights(const float* __restrict__ W1, const float* __restrict__ Wres,
                                    const float* __restrict__ W2,
                                    unsigned short* __restrict__ BT1,
                                    unsigned short* __restrict__ BT2) {
  int i = blockIdx.x * blockDim.x + threadIdx.x;
  if (i < 256 * 256) {
    int n = i >> 8, k = i & 255;
    float v = (n < 128) ? W1[k * 128 + n] : Wres[k * 128 + (n - 128)];
    BT1[i] = f2bf(v);
  } else if (i < 256 * 256 + 128 * 128) {
    int j = i - 256 * 256;
    int n = j >> 7, k = j & 127;
    BT2[j] = f2bf(W2[k * 128 + n]);
  }
}

// ---------------------------------------------------------------- GEMM1 (MFMA)
// C[M x 256] = A[M x 256] (fp32 -> bf16 staged) @ BT[256 x 256] (n-major).
// 256 thr / 4 waves, tile 64(M) x 256(N); wave owns 64-wide n-slice.
// Cols <128 -> C0 bf16; cols >=128 -> C1 fp32. LDS rows padded to 40 shorts.

static __global__ __launch_bounds__(256)
void gemm1_mfma(const float* __restrict__ A, const unsigned short* __restrict__ BT,
                unsigned short* __restrict__ C0, float* __restrict__ C1, int M) {
  __shared__ unsigned short As[64 * 40];
  __shared__ unsigned short Bs[256 * 40];
  int t = threadIdx.x;
  int wv = t >> 6, lane = t & 63;
  int quad = lane >> 4, l15 = lane & 15;
  int m0 = blockIdx.x * 64;

  f32x4 acc[4][4];
#pragma unroll
  for (int i = 0; i < 4; ++i)
#pragma unroll
    for (int j = 0; j < 4; ++j) acc[i][j] = (f32x4){0.f, 0.f, 0.f, 0.f};

  int ar = t >> 2;
  int ac = (t & 3) * 8;
  bool avalid = (m0 + ar) < M;
  const float* Arow = A + (size_t)(m0 + ar) * 256 + ac;
  const unsigned short* Brow = BT + (size_t)t * 256;

  for (int k0 = 0; k0 < 256; k0 += 32) {
    float4 a0 = make_float4(0.f, 0.f, 0.f, 0.f), a1 = a0;
    if (avalid) {
      a0 = *(const float4*)(Arow + k0);
      a1 = *(const float4*)(Arow + k0 + 4);
    }
    short8 av;
    av[0] = (short)f2bf(a0.x); av[1] = (short)f2bf(a0.y);
    av[2] = (short)f2bf(a0.z); av[3] = (short)f2bf(a0.w);
    av[4] = (short)f2bf(a1.x); av[5] = (short)f2bf(a1.y);
    av[6] = (short)f2bf(a1.z); av[7] = (short)f2bf(a1.w);
    *(short8*)&As[ar * 40 + ac] = av;

    short8 b0 = *(const short8*)(Brow + k0);
    short8 b1 = *(const short8*)(Brow + k0 + 8);
    short8 b2 = *(const short8*)(Brow + k0 + 16);
    short8 b3 = *(const short8*)(Brow + k0 + 24);
    *(short8*)&Bs[t * 40 + 0]  = b0;
    *(short8*)&Bs[t * 40 + 8]  = b1;
    *(short8*)&Bs[t * 40 + 16] = b2;
    *(short8*)&Bs[t * 40 + 24] = b3;
    __syncthreads();

    short8 af[4], bf[4];
#pragma unroll
    for (int mt = 0; mt < 4; ++mt)
      af[mt] = *(const short8*)&As[(mt * 16 + l15) * 40 + quad * 8];
#pragma unroll
    for (int nt = 0; nt < 4; ++nt)
      bf[nt] = *(const short8*)&Bs[(wv * 64 + nt * 16 + l15) * 40 + quad * 8];
#pragma unroll
    for (int mt = 0; mt < 4; ++mt)
#pragma unroll
      for (int nt = 0; nt < 4; ++nt)
        acc[mt][nt] = __builtin_amdgcn_mfma_f32_16x16x32_bf16(af[mt], bf[nt], acc[mt][nt], 0, 0, 0);
    __syncthreads();
  }

  int nbase = wv * 64;
#pragma unroll
  for (int mt = 0; mt < 4; ++mt) {
#pragma unroll
    for (int nt = 0; nt < 4; ++nt) {
      int n = nbase + nt * 16 + l15;
#pragma unroll
      for (int reg = 0; reg < 4; ++reg) {
        size_t m = (size_t)(m0 + mt * 16 + quad * 4 + reg);
        if (nbase < 128) C0[m * 128 + n] = f2bf(acc[mt][nt][reg]);
        else             C1[m * 128 + (n - 128)] = acc[mt][nt][reg];
      }
    }
  }
}

// ---------------------------------------------------------------- GEMM2 (MFMA)

static __global__ __launch_bounds__(256)
void gemm2_mfma(const unsigned short* __restrict__ A, const unsigned short* __restrict__ BT,
                unsigned short* __restrict__ C, int Mp) {
  __shared__ unsigned short As[128 * 40];
  __shared__ unsigned short Bs[128 * 40];
  int t = threadIdx.x;
  int wv = t >> 6, lane = t & 63;
  int quad = lane >> 4, l15 = lane & 15;
  int m0 = blockIdx.x * 128;

  f32x4 acc[4][4];
#pragma unroll
  for (int i = 0; i < 4; ++i)
#pragma unroll
    for (int j = 0; j < 4; ++j) acc[i][j] = (f32x4){0.f, 0.f, 0.f, 0.f};

  int sr = t >> 1, sc = (t & 1) * 16;

  for (int k0 = 0; k0 < 128; k0 += 32) {
    short8 a0 = *(const short8*)(A + (size_t)(m0 + sr) * 128 + k0 + sc);
    short8 a1 = *(const short8*)(A + (size_t)(m0 + sr) * 128 + k0 + sc + 8);
    *(short8*)&As[sr * 40 + sc]     = a0;
    *(short8*)&As[sr * 40 + sc + 8] = a1;
    short8 b0 = *(const short8*)(BT + (size_t)sr * 128 + k0 + sc);
    short8 b1 = *(const short8*)(BT + (size_t)sr * 128 + k0 + sc + 8);
    *(short8*)&Bs[sr * 40 + sc]     = b0;
    *(short8*)&Bs[sr * 40 + sc + 8] = b1;
    __syncthreads();

    int mb = (wv >> 1) * 64, nb = (wv & 1) * 64;
    short8 af[4], bf[4];
#pragma unroll
    for (int mt = 0; mt < 4; ++mt)
      af[mt] = *(const short8*)&As[(mb + mt * 16 + l15) * 40 + quad * 8];
#pragma unroll
    for (int nt = 0; nt < 4; ++nt)
      bf[nt] = *(const short8*)&Bs[(nb + nt * 16 + l15) * 40 + quad * 8];
#pragma unroll
    for (int mt = 0; mt < 4; ++mt)
#pragma unroll
      for (int nt = 0; nt < 4; ++nt)
        acc[mt][nt] = __builtin_amdgcn_mfma_f32_16x16x32_bf16(af[mt], bf[nt], acc[mt][nt], 0, 0, 0);
    __syncthreads();
  }

  int mb = (wv >> 1) * 64, nb = (wv & 1) * 64;
#pragma unroll
  for (int mt = 0; mt < 4; ++mt)
#pragma unroll
    for (int nt = 0; nt < 4; ++nt) {
      int n = nb + nt * 16 + l15;
#pragma unroll
      for (int reg = 0; reg < 4; ++reg) {
        size_t m = (size_t)(m0 + mb + mt * 16 + quad * 4 + reg);
        C[m * 128 + n] = f2bf(acc[mt][nt][reg]);
      }
    }
  (void)Mp;
}

// ---------------------------------------------------------------- propagation core
// One wave per destination node; lane holds 2 channels (one bf16x2 word).
// Stored edge weight = dis[src]*ew; destination dis factor applied once at end:
// agg = d * (d*h[w] + sum wt'_k h[src_k]).

#define PROP_GATHER_BODY                                                        \
  int c0 = lane * 2;                                                            \
  float d = dis[w];                                                             \
  float acc0, acc1;                                                             \
  {                                                                             \
    unsigned int u = Hsrc[(size_t)w * 64 + lane];                               \
    acc0 = d * __uint_as_float(u << 16);                                        \
    acc1 = d * __uint_as_float(u & 0xffff0000u);                                \
  }                                                                             \
  int s = start[w], n = cnt[w];                                                 \
  int k = 0;                                                                    \
  while (k < n) {                                                               \
    int chunk = min(n - k, 64);                                                 \
    int idx = 0;                                                                \
    float wt = 0.f;                                                             \
    if (lane < chunk) {                                                         \
      long long ev = edges[s + k + lane];                                       \
      idx = (int)(unsigned int)(ev & 0xffffffffLL);                             \
      wt  = __int_as_float((int)(ev >> 32));                                    \
    }                                                                           \
    for (int j = 0; j < chunk; j += 8) {                                        \
      int   i0 = __shfl(idx, j + 0, 64), i1 = __shfl(idx, j + 1, 64);           \
      int   i2 = __shfl(idx, j + 2, 64), i3 = __shfl(idx, j + 3, 64);           \
      int   i4 = __shfl(idx, j + 4, 64), i5 = __shfl(idx, j + 5, 64);           \
      int   i6 = __shfl(idx, j + 6, 64), i7 = __shfl(idx, j + 7, 64);           \
      float w0 = __shfl(wt, j + 0, 64), w1 = __shfl(wt, j + 1, 64);             \
      float w2 = __shfl(wt, j + 2, 64), w3 = __shfl(wt, j + 3, 64);             \
      float w4 = __shfl(wt, j + 4, 64), w5 = __shfl(wt, j + 5, 64);             \
      float w6 = __shfl(wt, j + 6, 64), w7 = __shfl(wt, j + 7, 64);             \
      unsigned int u0 = Hsrc[(size_t)i0 * 64 + lane];                           \
      unsigned int u1 = Hsrc[(size_t)i1 * 64 + lane];                           \
      unsigned int u2 = Hsrc[(size_t)i2 * 64 + lane];                           \
      unsigned int u3 = Hsrc[(size_t)i3 * 64 + lane];                           \
      unsigned int u4 = Hsrc[(size_t)i4 * 64 + lane];                           \
      unsigned int u5 = Hsrc[(size_t)i5 * 64 + lane];                           \
      unsigned int u6 = Hsrc[(size_t)i6 * 64 + lane];                           \
      unsigned int u7 = Hsrc[(size_t)i7 * 64 + lane];                           \
      acc0 = fmaf(w0, __uint_as_float(u0 << 16), acc0);                         \
      acc1 = fmaf(w0, __uint_as_float(u0 & 0xffff0000u), acc1);                 \
      acc0 = fmaf(w1, __uint_as_float(u1 << 16), acc0);                         \
      acc1 = fmaf(w1, __uint_as_float(u1 & 0xffff0000u), acc1);                 \
      acc0 = fmaf(w2, __uint_as_float(u2 << 16), acc0);                         \
      acc1 = fmaf(w2, __uint_as_float(u2 & 0xffff0000u), acc1);                 \
      acc0 = fmaf(w3, __uint_as_float(u3 << 16), acc0);                         \
      acc1 = fmaf(w3, __uint_as_float(u3 & 0xffff0000u), acc1);                 \
      acc0 = fmaf(w4, __uint_as_float(u4 << 16), acc0);                         \
      acc1 = fmaf(w4, __uint_as_float(u4 & 0xffff0000u), acc1);                 \
      acc0 = fmaf(w5, __uint_as_float(u5 << 16), acc0);                         \
      acc1 = fmaf(w5, __uint_as_float(u5 & 0xffff0000u), acc1);                 \
      acc0 = fmaf(w6, __uint_as_float(u6 << 16), acc0);                         \
      acc1 = fmaf(w6, __uint_as_float(u6 & 0xffff0000u), acc1);                 \
      acc0 = fmaf(w7, __uint_as_float(u7 << 16), acc0);                         \
      acc1 = fmaf(w7, __uint_as_float(u7 & 0xffff0000u), acc1);                 \
    }                                                                           \
    k += chunk;                                                                 \
  }                                                                             \
  acc0 *= d;                                                                    \
  acc1 *= d;

// prop1: h1 = relu(bn1(agg + b1)) -> bf16 packed output
static __global__ __launch_bounds__(256)
void prop128_bf16out(const unsigned int* __restrict__ Hsrc,
                     const int* __restrict__ start, const int* __restrict__ cnt,
                     const long long* __restrict__ edges,
                     const float* __restrict__ dis,
                     const float* __restrict__ bvec,
                     const float* __restrict__ g, const float* __restrict__ be,
                     const float* __restrict__ mean, const float* __restrict__ var,
                     unsigned int* __restrict__ Outb, int N) {
  int w = (int)((blockIdx.x * blockDim.x + threadIdx.x) >> 6);
  int lane = threadIdx.x & 63;
  if (w >= N) return;
  PROP_GATHER_BODY
  float x0 = acc0 + bvec[c0];
  float x1 = acc1 + bvec[c0 + 1];
  float s0 = g[c0] * rsqrtf(var[c0] + BN_EPS);
  float s1 = g[c0 + 1] * rsqrtf(var[c0 + 1] + BN_EPS);
  x0 = fmaxf((x0 - mean[c0]) * s0 + be[c0], 0.f);
  x1 = fmaxf((x1 - mean[c0 + 1]) * s1 + be[c0 + 1], 0.f);
  unsigned int packed = (unsigned int)f2bf(x0) | ((unsigned int)f2bf(x1) << 16);
  Outb[(size_t)w * 64 + lane] = packed;
}

// prop2: h2 = relu(bn2(agg + b2 + res)); fused h3[w] = dot(h2_row, W3)
static __global__ __launch_bounds__(256)
void prop128_w3out(const unsigned int* __restrict__ Hsrc,
                   const int* __restrict__ start, const int* __restrict__ cnt,
                   const long long* __restrict__ edges,
                   const float* __restrict__ dis,
                   const float* __restrict__ bvec,
                   const float* __restrict__ g, const float* __restrict__ be,
                   const float* __restrict__ mean, const float* __restrict__ var,
                   const float* __restrict__ res, const float* __restrict__ W3,
                   float* __restrict__ h3, int N) {
  int w = (int)((blockIdx.x * blockDim.x + threadIdx.x) >> 6);
  int lane = threadIdx.x & 63;
  if (w >= N) return;
  PROP_GATHER_BODY
  float x0 = acc0 + bvec[c0] + res[(size_t)w * 128 + c0];
  float x1 = acc1 + bvec[c0 + 1] + res[(size_t)w * 128 + c0 + 1];
  float s0 = g[c0] * rsqrtf(var[c0] + BN_EPS);
  float s1 = g[c0 + 1] * rsqrtf(var[c0 + 1] + BN_EPS);
  x0 = fmaxf((x0 - mean[c0]) * s0 + be[c0], 0.f);
  x1 = fmaxf((x1 - mean[c0 + 1]) * s1 + be[c0 + 1], 0.f);
  float v = x0 * W3[c0] + x1 * W3[c0 + 1];
#pragma unroll
  for (int off = 32; off > 0; off >>= 1) v += __shfl_down(v, off, 64);
  if (lane == 0) h3[w] = v;
}

// ---------------------------------------------------------------- final 1-wide propagation

static __global__ void prop3_kernel(const float* __restrict__ h3,
                                    const int* __restrict__ start, const int* __restrict__ cnt,
                                    const long long* __restrict__ edges,
                                    const float* __restrict__ dis, const float* __restrict__ b3,
                                    float* __restrict__ out, int N) {
  int i = blockIdx.x * blockDim.x + threadIdx.x;
  if (i >= N) return;
  float d = dis[i];
  float acc = d * h3[i];
  int s = start[i], n = cnt[i];
  for (int k = 0; k < n; ++k) {
    long long ev = edges[s + k];
    int src = (int)(unsigned int)(ev & 0xffffffffLL);
    float wt = __int_as_float((int)(ev >> 32));
    acc = fmaf(wt, h3[src], acc);
  }
  out[i] = acc * d + b3[0];
}

// ---------------------------------------------------------------- launch

extern "C" void kernel_launch(void* const* d_in, const int* in_sizes, int n_in,
                              void* d_out, int out_size, void* d_ws, size_t ws_size,
                              hipStream_t stream) {
  const float* x    = (const float*)d_in[0];
  const int*   ei   = (const int*)d_in[1];
  const float* ew   = (const float*)d_in[2];
  const float* W1   = (const float*)d_in[3];
  const float* b1   = (const float*)d_in[4];
  const float* W2   = (const float*)d_in[5];
  const float* b2   = (const float*)d_in[6];
  const float* W3   = (const float*)d_in[7];
  const float* b3   = (const float*)d_in[8];
  const float* Wres = (const float*)d_in[9];
  const float* g1   = (const float*)d_in[10];
  const float* be1  = (const float*)d_in[11];
  const float* m1   = (const float*)d_in[12];
  const float* v1   = (const float*)d_in[13];
  const float* g2   = (const float*)d_in[14];
  const float* be2  = (const float*)d_in[15];
  const float* m2   = (const float*)d_in[16];
  const float* v2   = (const float*)d_in[17];

  int Hh = in_sizes[4];            // 128
  int V  = in_sizes[3] / Hh;       // 256
  int N  = in_sizes[0] / V;        // 100000
  int E  = in_sizes[2];            // 1600000
  const int* row = ei;
  const int* col = ei + E;

  int Mp = ((N + 127) / 128) * 128;

  char* p = (char*)d_ws;
  auto alloc = [&](size_t bytes) -> char* {
    char* r = p;
    p += (bytes + 255) & ~(size_t)255;
    return r;
  };
  unsigned long long* packed = (unsigned long long*)alloc((size_t)N * 8);
  float* dis    = (float*)alloc((size_t)N * 4);
  int*   cnt    = (int*)  alloc((size_t)N * 4);
  int*   startA = (int*)  alloc((size_t)N * 4);
  int*   blkSum = (int*)  alloc(256 * 4);
  int*   blkOff = (int*)  alloc(256 * 4);
  unsigned short* rank = (unsigned short*)alloc((size_t)E * 2);
  long long* edges = (long long*)alloc((size_t)E * 8);
  float* h3     = (float*)alloc((size_t)N * 4);
  unsigned short* BT1 = (unsigned short*)alloc((size_t)256 * 256 * 2);
  unsigned short* BT2 = (unsigned short*)alloc((size_t)128 * 128 * 2);
  unsigned short* bufG  = (unsigned short*)alloc((size_t)Mp * 128 * 2);  // h0, then h1W2 (bf16)
  unsigned short* bufH1 = (unsigned short*)alloc((size_t)Mp * 128 * 2);  // h1 bf16
  float* bufRes = (float*)alloc((size_t)Mp * 128 * 4);                   // x@Wres fp32
  (void)ws_size; (void)n_in; (void)out_size;

  int TB = 256;
  hipMemsetAsync(packed, 0, (size_t)N * 8, stream);
  hist_kernel<<<(E + TB - 1) / TB, TB, 0, stream>>>(col, ew, packed, rank, E);
  unpack_kernel<<<(N + TB - 1) / TB, TB, 0, stream>>>(packed, dis, cnt, N);

  int nb = (N + SCAN_B * SCAN_I - 1) / (SCAN_B * SCAN_I);
  scanA<<<nb, SCAN_B, 0, stream>>>(cnt, startA, blkSum, N);
  scanB<<<1, 256, 0, stream>>>(blkSum, blkOff, nb);
  scanC<<<(N + TB - 1) / TB, TB, 0, stream>>>(startA, blkOff, N);
  place_kernel<<<(E + TB - 1) / TB, TB, 0, stream>>>(row, col, ew, dis, startA, rank, edges, E);

  cast_weights<<<(256 * 256 + 128 * 128 + TB - 1) / TB, TB, 0, stream>>>(W1, Wres, W2, BT1, BT2);

  // GEMM1: x @ [W1|Wres] -> bufG (bf16), bufRes (fp32)
  gemm1_mfma<<<Mp / 64, 256, 0, stream>>>(x, BT1, bufG, bufRes, N);

  // prop1: h1 = relu(bn1(agg(h0) + b1)) -> bufH1 (bf16)
  int propBlocks = (int)(((size_t)N * 64 + TB - 1) / TB);
  prop128_bf16out<<<propBlocks, TB, 0, stream>>>((const unsigned int*)bufG, startA, cnt,
                                                 edges, dis, b1, g1, be1, m1, v1,
                                                 (unsigned int*)bufH1, N);

  // GEMM2: h1 @ W2 -> bufG (bf16, reused)
  gemm2_mfma<<<Mp / 128, 256, 0, stream>>>(bufH1, BT2, bufG, Mp);

  // prop2 + fused W3: h3 = relu(bn2(agg(h1W2) + b2 + res)) . W3
  prop128_w3out<<<propBlocks, TB, 0, stream>>>((const unsigned int*)bufG, startA, cnt,
                                               edges, dis, b2, g2, be2, m2, v2,
                                               bufRes, W3, h3, N);

  // out = agg(h3) + b3
  prop3_kernel<<<(N + TB - 1) / TB, TB, 0, stream>>>(h3, startA, cnt, edges,
                                                     dis, b3, (float*)d_out, N);
}

// Round 7
// 503.891 us; speedup vs baseline: 2.0471x; 1.0460x over previous
//
#include <hip/hip_runtime.h>
#include <hip/hip_bf16.h>

#define BN_EPS 1e-5f

using short8 = __attribute__((ext_vector_type(8))) short;
using f32x4  = __attribute__((ext_vector_type(4))) float;

#define FIX_SCALE 1048576.0f          // 2^20
#define FIX_MASK  ((1ULL << 42) - 1)
#define CNT_ONE   (1ULL << 42)

static __device__ __forceinline__ unsigned short f2bf(float f) {
  unsigned int u = __float_as_uint(f);
  unsigned int r = (u + 0x7fffu + ((u >> 16) & 1u)) >> 16;
  return (unsigned short)r;
}

// ------------------------------------------------- weight cast (bf16, n-major)
// Must run BEFORE the fused kernel (produces BT1 consumed by its gemm1 half).

static __global__ void cast_weights(const float* __restrict__ W1, const float* __restrict__ Wres,
                                    const float* __restrict__ W2,
                                    unsigned short* __restrict__ BT1,
                                    unsigned short* __restrict__ BT2) {
  int i = blockIdx.x * blockDim.x + threadIdx.x;
  if (i < 256 * 256) {
    int n = i >> 8, k = i & 255;
    float v = (n < 128) ? W1[k * 128 + n] : Wres[k * 128 + (n - 128)];
    BT1[i] = f2bf(v);
  } else if (i < 256 * 256 + 128 * 128) {
    int j = i - 256 * 256;
    int n = j >> 7, k = j & 127;
    BT2[j] = f2bf(W2[k * 128 + n]);
  }
}

// ---------------------------------------------------------------- fused GEMM1 + hist
// Blocks [0, gemmBlocks): GEMM1  C[M x 256] = A(fp32->bf16) @ BT1 (n-major bf16);
//   cols<128 -> C0 bf16, cols>=128 -> C1 fp32. Latency-bound (MFMA+HBM pipes).
// Blocks [gemmBlocks, gemmBlocks+histBlocks): degree histogram — one packed
//   64-bit atomic per edge (cnt in [63:42], fixed-point ew-sum in [41:0]);
//   atomic return gives edge's insertion rank. Atomic-pipe-bound, ~0% VALU.
// Disjoint resources -> co-scheduling hides one behind the other.

static __global__ __launch_bounds__(256)
void fused_gemm1_hist(const float* __restrict__ A, const unsigned short* __restrict__ BT,
                      unsigned short* __restrict__ C0, float* __restrict__ C1, int M,
                      const int* __restrict__ col, const float* __restrict__ ew,
                      unsigned long long* __restrict__ packed,
                      unsigned short* __restrict__ rank, int E, int gemmBlocks) {
  __shared__ unsigned short As[64 * 40];
  __shared__ unsigned short Bs[256 * 40];

  if (blockIdx.x >= gemmBlocks) {
    // ---------------- hist half
    int e = (blockIdx.x - gemmBlocks) * blockDim.x + threadIdx.x;
    if (e < E) {
      int c = col[e];
      unsigned long long fx = (unsigned long long)(unsigned int)(ew[e] * FIX_SCALE + 0.5f);
      unsigned long long old = atomicAdd(&packed[c], CNT_ONE | fx);
      rank[e] = (unsigned short)(old >> 42);
    }
    return;
  }

  // ---------------- gemm1 half
  int t = threadIdx.x;
  int wv = t >> 6, lane = t & 63;
  int quad = lane >> 4, l15 = lane & 15;
  int m0 = blockIdx.x * 64;

  f32x4 acc[4][4];
#pragma unroll
  for (int i = 0; i < 4; ++i)
#pragma unroll
    for (int j = 0; j < 4; ++j) acc[i][j] = (f32x4){0.f, 0.f, 0.f, 0.f};

  int ar = t >> 2;
  int ac = (t & 3) * 8;
  bool avalid = (m0 + ar) < M;
  const float* Arow = A + (size_t)(m0 + ar) * 256 + ac;
  const unsigned short* Brow = BT + (size_t)t * 256;

  for (int k0 = 0; k0 < 256; k0 += 32) {
    float4 a0 = make_float4(0.f, 0.f, 0.f, 0.f), a1 = a0;
    if (avalid) {
      a0 = *(const float4*)(Arow + k0);
      a1 = *(const float4*)(Arow + k0 + 4);
    }
    short8 av;
    av[0] = (short)f2bf(a0.x); av[1] = (short)f2bf(a0.y);
    av[2] = (short)f2bf(a0.z); av[3] = (short)f2bf(a0.w);
    av[4] = (short)f2bf(a1.x); av[5] = (short)f2bf(a1.y);
    av[6] = (short)f2bf(a1.z); av[7] = (short)f2bf(a1.w);
    *(short8*)&As[ar * 40 + ac] = av;

    short8 b0 = *(const short8*)(Brow + k0);
    short8 b1 = *(const short8*)(Brow + k0 + 8);
    short8 b2 = *(const short8*)(Brow + k0 + 16);
    short8 b3 = *(const short8*)(Brow + k0 + 24);
    *(short8*)&Bs[t * 40 + 0]  = b0;
    *(short8*)&Bs[t * 40 + 8]  = b1;
    *(short8*)&Bs[t * 40 + 16] = b2;
    *(short8*)&Bs[t * 40 + 24] = b3;
    __syncthreads();

    short8 af[4], bf[4];
#pragma unroll
    for (int mt = 0; mt < 4; ++mt)
      af[mt] = *(const short8*)&As[(mt * 16 + l15) * 40 + quad * 8];
#pragma unroll
    for (int nt = 0; nt < 4; ++nt)
      bf[nt] = *(const short8*)&Bs[(wv * 64 + nt * 16 + l15) * 40 + quad * 8];
#pragma unroll
    for (int mt = 0; mt < 4; ++mt)
#pragma unroll
      for (int nt = 0; nt < 4; ++nt)
        acc[mt][nt] = __builtin_amdgcn_mfma_f32_16x16x32_bf16(af[mt], bf[nt], acc[mt][nt], 0, 0, 0);
    __syncthreads();
  }

  int nbase = wv * 64;
#pragma unroll
  for (int mt = 0; mt < 4; ++mt) {
#pragma unroll
    for (int nt = 0; nt < 4; ++nt) {
      int n = nbase + nt * 16 + l15;
#pragma unroll
      for (int reg = 0; reg < 4; ++reg) {
        size_t m = (size_t)(m0 + mt * 16 + quad * 4 + reg);
        if (nbase < 128) C0[m * 128 + n] = f2bf(acc[mt][nt][reg]);
        else             C1[m * 128 + (n - 128)] = acc[mt][nt][reg];
      }
    }
  }
}

// ---------------------------------------------------------------- scan (unpack folded in)

#define SCAN_B 256
#define SCAN_I 4
static __global__ void scanA(const unsigned long long* __restrict__ packed,
                             float* __restrict__ dis, int* __restrict__ cnt,
                             int* __restrict__ start, int* __restrict__ blkSum, int N) {
  __shared__ int sh[SCAN_B];
  int t = threadIdx.x;
  int base = blockIdx.x * SCAN_B * SCAN_I + t * SCAN_I;
  int v[SCAN_I];
  int tot = 0;
#pragma unroll
  for (int j = 0; j < SCAN_I; ++j) {
    if (base + j < N) {
      unsigned long long pv = packed[base + j];
      v[j] = (int)(pv >> 42);
      cnt[base + j] = v[j];
      float deg = 1.0f + (float)(pv & FIX_MASK) * (1.0f / FIX_SCALE);
      dis[base + j] = rsqrtf(deg);
    } else v[j] = 0;
    tot += v[j];
  }
  sh[t] = tot;
  __syncthreads();
  int self = tot;
  for (int off = 1; off < SCAN_B; off <<= 1) {
    int add = (t >= off) ? sh[t - off] : 0;
    __syncthreads();
    sh[t] += add;
    __syncthreads();
  }
  int excl = sh[t] - self;
  if (t == SCAN_B - 1) blkSum[blockIdx.x] = sh[t];
  int run = excl;
#pragma unroll
  for (int j = 0; j < SCAN_I; ++j) {
    if (base + j < N) start[base + j] = run;
    run += v[j];
  }
}

static __global__ void scanB(const int* __restrict__ blkSum, int* __restrict__ blkOff, int nb) {
  __shared__ int sh[256];
  int t = threadIdx.x;
  int v = (t < nb) ? blkSum[t] : 0;
  sh[t] = v;
  __syncthreads();
  for (int off = 1; off < 256; off <<= 1) {
    int add = (t >= off) ? sh[t - off] : 0;
    __syncthreads();
    sh[t] += add;
    __syncthreads();
  }
  if (t < nb) blkOff[t] = sh[t] - v;
}

static __global__ void scanC(int* start, const int* __restrict__ blkOff, int N) {
  int i = blockIdx.x * blockDim.x + threadIdx.x;
  if (i < N) start[i] += blkOff[i / (SCAN_B * SCAN_I)];
}

// atomic-free placement: pos = start[col] + rank. edges[pos] = (src, dis[src]*ew)
static __global__ void place_kernel(const int* __restrict__ row, const int* __restrict__ col,
                                    const float* __restrict__ ew, const float* __restrict__ dis,
                                    const int* __restrict__ start,
                                    const unsigned short* __restrict__ rank,
                                    long long* __restrict__ edges, int E) {
  int e = blockIdx.x * blockDim.x + threadIdx.x;
  if (e < E) {
    int r = row[e], c = col[e];
    int pos = start[c] + (int)rank[e];
    float nrm = dis[r] * ew[e];
    long long v = ((long long)__float_as_int(nrm) << 32) | (unsigned int)r;
    __builtin_nontemporal_store(v, &edges[pos]);
  }
}

// ---------------------------------------------------------------- GEMM2 (MFMA)

static __global__ __launch_bounds__(256)
void gemm2_mfma(const unsigned short* __restrict__ A, const unsigned short* __restrict__ BT,
                unsigned short* __restrict__ C, int Mp) {
  __shared__ unsigned short As[128 * 40];
  __shared__ unsigned short Bs[128 * 40];
  int t = threadIdx.x;
  int wv = t >> 6, lane = t & 63;
  int quad = lane >> 4, l15 = lane & 15;
  int m0 = blockIdx.x * 128;

  f32x4 acc[4][4];
#pragma unroll
  for (int i = 0; i < 4; ++i)
#pragma unroll
    for (int j = 0; j < 4; ++j) acc[i][j] = (f32x4){0.f, 0.f, 0.f, 0.f};

  int sr = t >> 1, sc = (t & 1) * 16;

  for (int k0 = 0; k0 < 128; k0 += 32) {
    short8 a0 = *(const short8*)(A + (size_t)(m0 + sr) * 128 + k0 + sc);
    short8 a1 = *(const short8*)(A + (size_t)(m0 + sr) * 128 + k0 + sc + 8);
    *(short8*)&As[sr * 40 + sc]     = a0;
    *(short8*)&As[sr * 40 + sc + 8] = a1;
    short8 b0 = *(const short8*)(BT + (size_t)sr * 128 + k0 + sc);
    short8 b1 = *(const short8*)(BT + (size_t)sr * 128 + k0 + sc + 8);
    *(short8*)&Bs[sr * 40 + sc]     = b0;
    *(short8*)&Bs[sr * 40 + sc + 8] = b1;
    __syncthreads();

    int mb = (wv >> 1) * 64, nb = (wv & 1) * 64;
    short8 af[4], bf[4];
#pragma unroll
    for (int mt = 0; mt < 4; ++mt)
      af[mt] = *(const short8*)&As[(mb + mt * 16 + l15) * 40 + quad * 8];
#pragma unroll
    for (int nt = 0; nt < 4; ++nt)
      bf[nt] = *(const short8*)&Bs[(nb + nt * 16 + l15) * 40 + quad * 8];
#pragma unroll
    for (int mt = 0; mt < 4; ++mt)
#pragma unroll
      for (int nt = 0; nt < 4; ++nt)
        acc[mt][nt] = __builtin_amdgcn_mfma_f32_16x16x32_bf16(af[mt], bf[nt], acc[mt][nt], 0, 0, 0);
    __syncthreads();
  }

  int mb = (wv >> 1) * 64, nb = (wv & 1) * 64;
#pragma unroll
  for (int mt = 0; mt < 4; ++mt)
#pragma unroll
    for (int nt = 0; nt < 4; ++nt) {
      int n = nb + nt * 16 + l15;
#pragma unroll
      for (int reg = 0; reg < 4; ++reg) {
        size_t m = (size_t)(m0 + mb + mt * 16 + quad * 4 + reg);
        C[m * 128 + n] = f2bf(acc[mt][nt][reg]);
      }
    }
  (void)Mp;
}

// ---------------------------------------------------------------- propagation core
// One wave per destination node; lane holds 2 channels (one bf16x2 word).
// Stored edge weight = dis[src]*ew; destination dis applied once at the end.

#define PROP_GATHER_BODY                                                        \
  int c0 = lane * 2;                                                            \
  float d = dis[w];                                                             \
  float acc0, acc1;                                                             \
  {                                                                             \
    unsigned int u = Hsrc[(size_t)w * 64 + lane];                               \
    acc0 = d * __uint_as_float(u << 16);                                        \
    acc1 = d * __uint_as_float(u & 0xffff0000u);                                \
  }                                                                             \
  int s = start[w], n = cnt[w];                                                 \
  int k = 0;                                                                    \
  while (k < n) {                                                               \
    int chunk = min(n - k, 64);                                                 \
    int idx = 0;                                                                \
    float wt = 0.f;                                                             \
    if (lane < chunk) {                                                         \
      long long ev = edges[s + k + lane];                                       \
      idx = (int)(unsigned int)(ev & 0xffffffffLL);                             \
      wt  = __int_as_float((int)(ev >> 32));                                    \
    }                                                                           \
    for (int j = 0; j < chunk; j += 8) {                                        \
      int   i0 = __shfl(idx, j + 0, 64), i1 = __shfl(idx, j + 1, 64);           \
      int   i2 = __shfl(idx, j + 2, 64), i3 = __shfl(idx, j + 3, 64);           \
      int   i4 = __shfl(idx, j + 4, 64), i5 = __shfl(idx, j + 5, 64);           \
      int   i6 = __shfl(idx, j + 6, 64), i7 = __shfl(idx, j + 7, 64);           \
      float w0 = __shfl(wt, j + 0, 64), w1 = __shfl(wt, j + 1, 64);             \
      float w2 = __shfl(wt, j + 2, 64), w3 = __shfl(wt, j + 3, 64);             \
      float w4 = __shfl(wt, j + 4, 64), w5 = __shfl(wt, j + 5, 64);             \
      float w6 = __shfl(wt, j + 6, 64), w7 = __shfl(wt, j + 7, 64);             \
      unsigned int u0 = Hsrc[(size_t)i0 * 64 + lane];                           \
      unsigned int u1 = Hsrc[(size_t)i1 * 64 + lane];                           \
      unsigned int u2 = Hsrc[(size_t)i2 * 64 + lane];                           \
      unsigned int u3 = Hsrc[(size_t)i3 * 64 + lane];                           \
      unsigned int u4 = Hsrc[(size_t)i4 * 64 + lane];                           \
      unsigned int u5 = Hsrc[(size_t)i5 * 64 + lane];                           \
      unsigned int u6 = Hsrc[(size_t)i6 * 64 + lane];                           \
      unsigned int u7 = Hsrc[(size_t)i7 * 64 + lane];                           \
      acc0 = fmaf(w0, __uint_as_float(u0 << 16), acc0);                         \
      acc1 = fmaf(w0, __uint_as_float(u0 & 0xffff0000u), acc1);                 \
      acc0 = fmaf(w1, __uint_as_float(u1 << 16), acc0);                         \
      acc1 = fmaf(w1, __uint_as_float(u1 & 0xffff0000u), acc1);                 \
      acc0 = fmaf(w2, __uint_as_float(u2 << 16), acc0);                         \
      acc1 = fmaf(w2, __uint_as_float(u2 & 0xffff0000u), acc1);                 \
      acc0 = fmaf(w3, __uint_as_float(u3 << 16), acc0);                         \
      acc1 = fmaf(w3, __uint_as_float(u3 & 0xffff0000u), acc1);                 \
      acc0 = fmaf(w4, __uint_as_float(u4 << 16), acc0);                         \
      acc1 = fmaf(w4, __uint_as_float(u4 & 0xffff0000u), acc1);                 \
      acc0 = fmaf(w5, __uint_as_float(u5 << 16), acc0);                         \
      acc1 = fmaf(w5, __uint_as_float(u5 & 0xffff0000u), acc1);                 \
      acc0 = fmaf(w6, __uint_as_float(u6 << 16), acc0);                         \
      acc1 = fmaf(w6, __uint_as_float(u6 & 0xffff0000u), acc1);                 \
      acc0 = fmaf(w7, __uint_as_float(u7 << 16), acc0);                         \
      acc1 = fmaf(w7, __uint_as_float(u7 & 0xffff0000u), acc1);                 \
    }                                                                           \
    k += chunk;                                                                 \
  }                                                                             \
  acc0 *= d;                                                                    \
  acc1 *= d;

// prop1: h1 = relu(bn1(agg + b1)) -> bf16 packed output
static __global__ __launch_bounds__(256)
void prop128_bf16out(const unsigned int* __restrict__ Hsrc,
                     const int* __restrict__ start, const int* __restrict__ cnt,
                     const long long* __restrict__ edges,
                     const float* __restrict__ dis,
                     const float* __restrict__ bvec,
                     const float* __restrict__ g, const float* __restrict__ be,
                     const float* __restrict__ mean, const float* __restrict__ var,
                     unsigned int* __restrict__ Outb, int N) {
  int w = (int)((blockIdx.x * blockDim.x + threadIdx.x) >> 6);
  int lane = threadIdx.x & 63;
  if (w >= N) return;
  PROP_GATHER_BODY
  float x0 = acc0 + bvec[c0];
  float x1 = acc1 + bvec[c0 + 1];
  float s0 = g[c0] * rsqrtf(var[c0] + BN_EPS);
  float s1 = g[c0 + 1] * rsqrtf(var[c0 + 1] + BN_EPS);
  x0 = fmaxf((x0 - mean[c0]) * s0 + be[c0], 0.f);
  x1 = fmaxf((x1 - mean[c0 + 1]) * s1 + be[c0 + 1], 0.f);
  unsigned int packed = (unsigned int)f2bf(x0) | ((unsigned int)f2bf(x1) << 16);
  Outb[(size_t)w * 64 + lane] = packed;
}

// prop2: h2 = relu(bn2(agg + b2 + res)); fused h3[w] = dot(h2_row, W3)
static __global__ __launch_bounds__(256)
void prop128_w3out(const unsigned int* __restrict__ Hsrc,
                   const int* __restrict__ start, const int* __restrict__ cnt,
                   const long long* __restrict__ edges,
                   const float* __restrict__ dis,
                   const float* __restrict__ bvec,
                   const float* __restrict__ g, const float* __restrict__ be,
                   const float* __restrict__ mean, const float* __restrict__ var,
                   const float* __restrict__ res, const float* __restrict__ W3,
                   float* __restrict__ h3, int N) {
  int w = (int)((blockIdx.x * blockDim.x + threadIdx.x) >> 6);
  int lane = threadIdx.x & 63;
  if (w >= N) return;
  PROP_GATHER_BODY
  float x0 = acc0 + bvec[c0] + res[(size_t)w * 128 + c0];
  float x1 = acc1 + bvec[c0 + 1] + res[(size_t)w * 128 + c0 + 1];
  float s0 = g[c0] * rsqrtf(var[c0] + BN_EPS);
  float s1 = g[c0 + 1] * rsqrtf(var[c0 + 1] + BN_EPS);
  x0 = fmaxf((x0 - mean[c0]) * s0 + be[c0], 0.f);
  x1 = fmaxf((x1 - mean[c0 + 1]) * s1 + be[c0 + 1], 0.f);
  float v = x0 * W3[c0] + x1 * W3[c0 + 1];
#pragma unroll
  for (int off = 32; off > 0; off >>= 1) v += __shfl_down(v, off, 64);
  if (lane == 0) h3[w] = v;
}

// ---------------------------------------------------------------- final 1-wide propagation

static __global__ void prop3_kernel(const float* __restrict__ h3,
                                    const int* __restrict__ start, const int* __restrict__ cnt,
                                    const long long* __restrict__ edges,
                                    const float* __restrict__ dis, const float* __restrict__ b3,
                                    float* __restrict__ out, int N) {
  int i = blockIdx.x * blockDim.x + threadIdx.x;
  if (i >= N) return;
  float d = dis[i];
  float acc = d * h3[i];
  int s = start[i], n = cnt[i];
  for (int k = 0; k < n; ++k) {
    long long ev = edges[s + k];
    int src = (int)(unsigned int)(ev & 0xffffffffLL);
    float wt = __int_as_float((int)(ev >> 32));
    acc = fmaf(wt, h3[src], acc);
  }
  out[i] = acc * d + b3[0];
}

// ---------------------------------------------------------------- launch

extern "C" void kernel_launch(void* const* d_in, const int* in_sizes, int n_in,
                              void* d_out, int out_size, void* d_ws, size_t ws_size,
                              hipStream_t stream) {
  const float* x    = (const float*)d_in[0];
  const int*   ei   = (const int*)d_in[1];
  const float* ew   = (const float*)d_in[2];
  const float* W1   = (const float*)d_in[3];
  const float* b1   = (const float*)d_in[4];
  const float* W2   = (const float*)d_in[5];
  const float* b2   = (const float*)d_in[6];
  const float* W3   = (const float*)d_in[7];
  const float* b3   = (const float*)d_in[8];
  const float* Wres = (const float*)d_in[9];
  const float* g1   = (const float*)d_in[10];
  const float* be1  = (const float*)d_in[11];
  const float* m1   = (const float*)d_in[12];
  const float* v1   = (const float*)d_in[13];
  const float* g2   = (const float*)d_in[14];
  const float* be2  = (const float*)d_in[15];
  const float* m2   = (const float*)d_in[16];
  const float* v2   = (const float*)d_in[17];

  int Hh = in_sizes[4];            // 128
  int V  = in_sizes[3] / Hh;       // 256
  int N  = in_sizes[0] / V;        // 100000
  int E  = in_sizes[2];            // 1600000
  const int* row = ei;
  const int* col = ei + E;

  int Mp = ((N + 127) / 128) * 128;

  char* p = (char*)d_ws;
  auto alloc = [&](size_t bytes) -> char* {
    char* r = p;
    p += (bytes + 255) & ~(size_t)255;
    return r;
  };
  unsigned long long* packed = (unsigned long long*)alloc((size_t)N * 8);
  float* dis    = (float*)alloc((size_t)N * 4);
  int*   cnt    = (int*)  alloc((size_t)N * 4);
  int*   startA = (int*)  alloc((size_t)N * 4);
  int*   blkSum = (int*)  alloc(256 * 4);
  int*   blkOff = (int*)  alloc(256 * 4);
  unsigned short* rank = (unsigned short*)alloc((size_t)E * 2);
  long long* edges = (long long*)alloc((size_t)E * 8);
  float* h3     = (float*)alloc((size_t)N * 4);
  unsigned short* BT1 = (unsigned short*)alloc((size_t)256 * 256 * 2);
  unsigned short* BT2 = (unsigned short*)alloc((size_t)128 * 128 * 2);
  unsigned short* bufG  = (unsigned short*)alloc((size_t)Mp * 128 * 2);  // h0, then h1W2 (bf16)
  unsigned short* bufH1 = (unsigned short*)alloc((size_t)Mp * 128 * 2);  // h1 bf16
  float* bufRes = (float*)alloc((size_t)Mp * 128 * 4);                   // x@Wres fp32
  (void)ws_size; (void)n_in; (void)out_size;

  int TB = 256;
  hipMemsetAsync(packed, 0, (size_t)N * 8, stream);
  cast_weights<<<(256 * 256 + 128 * 128 + TB - 1) / TB, TB, 0, stream>>>(W1, Wres, W2, BT1, BT2);

  // fused: GEMM1 (blocks [0,gB)) + hist (blocks [gB, gB+hB))
  int gB = Mp / 64;                       // note: Mp mult of 128 -> mult of 64
  int hB = (E + TB - 1) / TB;
  fused_gemm1_hist<<<gB + hB, TB, 0, stream>>>(x, BT1, bufG, bufRes, N,
                                               col, ew, packed, rank, E, gB);

  int nb = (N + SCAN_B * SCAN_I - 1) / (SCAN_B * SCAN_I);
  scanA<<<nb, SCAN_B, 0, stream>>>(packed, dis, cnt, startA, blkSum, N);
  scanB<<<1, 256, 0, stream>>>(blkSum, blkOff, nb);
  scanC<<<(N + TB - 1) / TB, TB, 0, stream>>>(startA, blkOff, N);
  place_kernel<<<(E + TB - 1) / TB, TB, 0, stream>>>(row, col, ew, dis, startA, rank, edges, E);

  // prop1: h1 = relu(bn1(agg(h0) + b1)) -> bufH1 (bf16)
  int propBlocks = (int)(((size_t)N * 64 + TB - 1) / TB);
  prop128_bf16out<<<propBlocks, TB, 0, stream>>>((const unsigned int*)bufG, startA, cnt,
                                                 edges, dis, b1, g1, be1, m1, v1,
                                                 (unsigned int*)bufH1, N);

  // GEMM2: h1 @ W2 -> bufG (bf16, reused)
  gemm2_mfma<<<Mp / 128, 256, 0, stream>>>(bufH1, BT2, bufG, Mp);

  // prop2 + fused W3: h3 = relu(bn2(agg(h1W2) + b2 + res)) . W3
  prop128_w3out<<<propBlocks, TB, 0, stream>>>((const unsigned int*)bufG, startA, cnt,
                                               edges, dis, b2, g2, be2, m2, v2,
                                               bufRes, W3, h3, N);

  // out = agg(h3) + b3
  prop3_kernel<<<(N + TB - 1) / TB, TB, 0, stream>>>(h3, startA, cnt, edges,
                                                     dis, b3, (float*)d_out, N);
}